// Round 5
// baseline (1646.323 us; speedup 1.0000x reference)
//
#include <hip/hip_runtime.h>
#include <stdint.h>

// Problem: B=32, N=512, E=1024, H=8, L=3, FF=2048, KD=128, DK=16
// Transport dtype (f32 vs bf16) detected on device; compute bf16 MFMA + f32 master h.

typedef __attribute__((ext_vector_type(8))) short short8;
typedef __attribute__((ext_vector_type(4))) float floatx4;

#define NORM_ 0.08838834764831845f   // 1/sqrt(128)

__device__ __forceinline__ float bf2f(unsigned short u) {
    union { unsigned int i; float f; } x; x.i = ((unsigned int)u) << 16; return x.f;
}
__device__ __forceinline__ unsigned short f2bf(float f) {  // RNE
    union { float f; unsigned int i; } x; x.f = f;
    unsigned int u = x.i;
    u += 0x7FFFu + ((u >> 16) & 1u);
    return (unsigned short)(u >> 16);
}
__device__ __forceinline__ void async_cp16(const void* g, void* l) {
    __builtin_amdgcn_global_load_lds((const __attribute__((address_space(1))) void*)g,
                                     (__attribute__((address_space(3))) void*)l, 16, 0, 0);
}
__device__ __forceinline__ floatx4 mfma16(short8 a, short8 b, floatx4 c) {
    return __builtin_amdgcn_mfma_f32_16x16x32_bf16(a, b, c, 0, 0, 0);
}
// inline-asm LDS read: opaque to the compiler's waitcnt pass (no hidden drains)
template<int IMM>
__device__ __forceinline__ short8 ds_read128(unsigned addr) {
    short8 r;
    asm volatile("ds_read_b128 %0, %1 offset:%2" : "=v"(r) : "v"(addr), "n"(IMM));
    return r;
}
// inline-asm global load (counts vmcnt; we manage waits manually)
template<int IMM>
__device__ __forceinline__ short8 gload128(const unsigned short* p) {
    short8 r;
    asm volatile("global_load_dwordx4 %0, %1, off offset:%2" : "=v"(r) : "v"(p), "n"(IMM));
    return r;
}

// ---- transport dtype detection -------------------------------------------
__global__ __launch_bounds__(256) void detect_dtype(const unsigned int* __restrict__ x,
                                                    int* __restrict__ flag)
{
    __shared__ int good, bad;
    if (threadIdx.x == 0) { good = 0; bad = 0; }
    __syncthreads();
    int g = 0, b = 0;
    for (int i = threadIdx.x; i < 4096; i += 256) {
        unsigned int lo = x[i] & 0xFFFFu;
        if (lo != 0u) {
            unsigned int e = (lo >> 7) & 0xFFu;
            if (e >= 90u && e <= 145u) ++g; else ++b;
        }
    }
    atomicAdd(&good, g); atomicAdd(&bad, b);
    __syncthreads();
    if (threadIdx.x == 0) *flag = (bad > good) ? 1 : 0;   // 1 = f32 transport
}

__global__ __launch_bounds__(256) void conv_to_bf16(const void* __restrict__ src,
                                                    unsigned short* __restrict__ dst,
                                                    int n, const int* __restrict__ flag)
{
    const int i = (blockIdx.x * 256 + threadIdx.x) * 8;
    if (i >= n) return;
    if (*flag) {
        const float* s = (const float*)src + i;
        floatx4 a = *(const floatx4*)s;
        floatx4 b = *(const floatx4*)(s + 4);
        short8 o;
        o[0] = (short)f2bf(a[0]); o[1] = (short)f2bf(a[1]);
        o[2] = (short)f2bf(a[2]); o[3] = (short)f2bf(a[3]);
        o[4] = (short)f2bf(b[0]); o[5] = (short)f2bf(b[1]);
        o[6] = (short)f2bf(b[2]); o[7] = (short)f2bf(b[3]);
        *(short8*)(dst + i) = o;
    } else {
        *(short8*)(dst + i) = *(const short8*)((const unsigned short*)src + i);
    }
}

__global__ __launch_bounds__(256) void init_h(const void* __restrict__ x,
                                              float* __restrict__ hf,
                                              unsigned short* __restrict__ hb,
                                              const int* __restrict__ flag)
{
    const size_t i = ((size_t)blockIdx.x * 256 + threadIdx.x) * 8;
    if (*flag) {
        const float* s = (const float*)x + i;
        floatx4 a = *(const floatx4*)s;
        floatx4 b = *(const floatx4*)(s + 4);
        short8 o;
        o[0] = (short)f2bf(a[0]); o[1] = (short)f2bf(a[1]);
        o[2] = (short)f2bf(a[2]); o[3] = (short)f2bf(a[3]);
        o[4] = (short)f2bf(b[0]); o[5] = (short)f2bf(b[1]);
        o[6] = (short)f2bf(b[2]); o[7] = (short)f2bf(b[3]);
        *(short8*)(hb + i) = o;
        *(floatx4*)(hf + i) = a;
        *(floatx4*)(hf + i + 4) = b;
    } else {
        short8 v = *(const short8*)((const unsigned short*)x + i);
        *(short8*)(hb + i) = v;
        #pragma unroll
        for (int e = 0; e < 8; ++e) hf[i + e] = bf2f((unsigned short)v[e]);
    }
}

__global__ __launch_bounds__(256) void mask_expand(const unsigned int* __restrict__ mraw,
                                                   float* __restrict__ maskf)
{
    __shared__ unsigned int r[4];
    if (threadIdx.x < 4) r[threadIdx.x] = 0;
    __syncthreads();
    unsigned int gt1 = 0, badb = 0, badh = 0, lo3f = 0;
    for (int i = threadIdx.x; i < 4096; i += 256) {
        unsigned int w = mraw[i];
        if (w > 1u) gt1 = 1;
        if (w & 0xFEFEFEFEu) badb = 1;
        unsigned int lo = w & 0xFFFFu, hi = w >> 16;
        if ((lo != 0u && lo != 0x3F80u) || (hi != 0u && hi != 0x3F80u)) badh = 1;
        if (lo == 0x3F80u) lo3f = 1;
    }
    if (gt1) atomicOr(&r[0], 1u);
    if (badb) atomicOr(&r[1], 1u);
    if (badh) atomicOr(&r[2], 1u);
    if (lo3f) atomicOr(&r[3], 1u);
    __syncthreads();
    int cls;
    if (!r[0]) cls = 0;
    else if (!r[1]) cls = 1;
    else if (!r[2]) cls = r[3] ? 2 : 3;
    else cls = 0;

    const int gid = blockIdx.x * 256 + threadIdx.x;
    bool m;
    if (cls == 0)      m = ((const int*)mraw)[gid] != 0;
    else if (cls == 1) m = ((const unsigned char*)mraw)[gid] != 0;
    else if (cls == 2) m = ((const unsigned short*)mraw)[gid] != 0;
    else               m = mraw[gid] != 0u;
    maskf[gid] = m ? 1.0f : 0.0f;
}

enum { EPI_NONE = 0, EPI_BIAS_RELU = 1, EPI_BIAS_RES = 2 };

// ---------------------------------------------------------------------------
// 128x128 tile kernel (proven) — used for QKV (N=128) and Wo (K=128).
// ---------------------------------------------------------------------------
template<int EPI>
__global__ __launch_bounds__(256) void gemm_bt(
    const unsigned short* __restrict__ A,
    const unsigned short* __restrict__ Bq,
    const unsigned short* __restrict__ Bk,
    const unsigned short* __restrict__ Bv,
    unsigned short* __restrict__ Cq,
    unsigned short* __restrict__ Ck,
    unsigned short* __restrict__ Cv,
    const unsigned short* __restrict__ bias,
    float* __restrict__ hf,
    unsigned short* __restrict__ hb,
    int N, int K)
{
    constexpr int BK = 64;
    __shared__ __align__(16) unsigned short As[2][128 * BK];   // 2 x 16 KB
    __shared__ __align__(16) unsigned short Bs[2][128 * BK];   // 2 x 16 KB

    const int t = threadIdx.x;
    const int lane = t & 63;
    const int wave = t >> 6;
    const int bm = blockIdx.x;
    const int bn = blockIdx.y;
    const int bz = blockIdx.z;

    const unsigned short* Bmat = (bz == 0) ? Bq : ((bz == 1) ? Bk : Bv);
    unsigned short* C = (bz == 0) ? Cq : ((bz == 1) ? Ck : Cv);

    const int wm = (wave >> 1) * 64;
    const int wn = (wave & 1) * 64;

    const int srow = t >> 3;                               // 0..31
    const int scol = (((t & 7) ^ ((t >> 3) & 7)) * 8);     // swizzled source col
    const unsigned short* Ag = A + (size_t)(bm * 128 + srow) * K + scol;
    const unsigned short* Bg = Bmat + (size_t)(bn * 128 + srow) * K + scol;
    const size_t gstep = (size_t)32 * K;                   // 32 rows per round

    const int fl = lane & 15;
    const int g = lane >> 4;
    const int s7 = fl & 7;
    const int swz0 = (g ^ s7) * 8;          // ks = 0 chunk
    const int swz1 = ((g + 4) ^ s7) * 8;    // ks = 32 chunk
    int aoff[4], boff[4];
    #pragma unroll
    for (int i = 0; i < 4; ++i) {
        aoff[i] = (wm + i * 16 + fl) * BK;
        boff[i] = (wn + i * 16 + fl) * BK;
    }

    floatx4 acc[4][4];
    #pragma unroll
    for (int i = 0; i < 4; ++i)
        #pragma unroll
        for (int j = 0; j < 4; ++j) {
            acc[i][j][0] = 0.f; acc[i][j][1] = 0.f;
            acc[i][j][2] = 0.f; acc[i][j][3] = 0.f;
        }

    const int NT = K / BK;

    #pragma unroll
    for (int r = 0; r < 4; ++r) {
        async_cp16(Ag + r * gstep, &As[0][t * 8 + r * 2048]);
        async_cp16(Bg + r * gstep, &Bs[0][t * 8 + r * 2048]);
    }

    for (int it = 0; it < NT; ++it) {
        const int cur = it & 1;
        if (it + 1 < NT) {
            const int nxt = cur ^ 1;
            const size_t koff = (size_t)(it + 1) * BK;
            #pragma unroll
            for (int r = 0; r < 4; ++r) {
                async_cp16(Ag + koff + r * gstep, &As[nxt][t * 8 + r * 2048]);
                async_cp16(Bg + koff + r * gstep, &Bs[nxt][t * 8 + r * 2048]);
            }
            asm volatile("s_waitcnt vmcnt(8)" ::: "memory");
        } else {
            asm volatile("s_waitcnt vmcnt(0)" ::: "memory");
        }
        asm volatile("s_barrier" ::: "memory");

        #pragma unroll
        for (int ks = 0; ks < 2; ++ks) {
            const int sw = ks ? swz1 : swz0;
            short8 af[4], bfr[4];
            #pragma unroll
            for (int i = 0; i < 4; ++i) af[i] = *(const short8*)&As[cur][aoff[i] + sw];
            #pragma unroll
            for (int j = 0; j < 4; ++j) bfr[j] = *(const short8*)&Bs[cur][boff[j] + sw];
            #pragma unroll
            for (int i = 0; i < 4; ++i)
                #pragma unroll
                for (int j = 0; j < 4; ++j)
                    acc[i][j] = __builtin_amdgcn_mfma_f32_16x16x32_bf16(af[i], bfr[j], acc[i][j], 0, 0, 0);
        }
        if (it + 1 < NT)
            asm volatile("s_barrier" ::: "memory");
    }

    const int r0 = (lane >> 4) * 4;
    #pragma unroll
    for (int j = 0; j < 4; ++j) {
        const int gcol = bn * 128 + wn + j * 16 + fl;
        float bval = 0.f;
        if (EPI != EPI_NONE) bval = bf2f(bias[gcol]);
        #pragma unroll
        for (int i = 0; i < 4; ++i) {
            const int growb = bm * 128 + wm + i * 16 + r0;
            #pragma unroll
            for (int r = 0; r < 4; ++r) {
                const size_t idx = (size_t)(growb + r) * N + gcol;
                float v = acc[i][j][r];
                if (EPI == EPI_NONE) {
                    C[idx] = f2bf(v);
                } else if (EPI == EPI_BIAS_RELU) {
                    v += bval;
                    v = v > 0.f ? v : 0.f;
                    C[idx] = f2bf(v);
                } else {
                    float nh = hf[idx] + v + bval;
                    hf[idx] = nh;
                    hb[idx] = f2bf(nh);
                }
            }
        }
    }
}

// ---------------------------------------------------------------------------
// FFN GEMM: 128x256 tile, BK=64, 512 threads = 8 waves of 64x64.
// A (activations) double-buffered in LDS (32 KB total).
// B (weights, L2-resident) read DIRECTLY global->VGPR, one tile ahead.
// Per K-tile: 2 barriers, 1 lgkmcnt(0), 1 counted vmcnt (never 0 mid-loop).
// All mainloop memory ops are inline asm -> no compiler-inserted drains.
// launch_bounds(512,2): 256-VGPR cap -> NO scratch spill (natural live set
// ~200 VGPR; the earlier (512,4)=128-cap forced hot-loop spilling).
// Accumulation order per element (ks0 then ks1 per tile, tiles ascending)
// is bit-identical to the proven gemm_bt path.
// ---------------------------------------------------------------------------
template<int EPI>
__global__ __launch_bounds__(512, 2) void gemm_ffn(
    const unsigned short* __restrict__ A,
    const unsigned short* __restrict__ Bmat,
    unsigned short* __restrict__ C,
    const unsigned short* __restrict__ bias,
    float* __restrict__ hf,
    unsigned short* __restrict__ hb,
    int N, int K)
{
    __shared__ __align__(16) unsigned short As[2][8192];   // 2 x 128 x 64 = 32 KB

    const int t = threadIdx.x;           // 0..511
    const int lane = t & 63;
    const int wave = t >> 6;             // 0..7
    const int bm = blockIdx.x;
    const int bn = blockIdx.y;

    const int wm = (wave >> 2) * 64;     // 2 row-groups of 64
    const int wn = (wave & 3) * 64;      // 4 col-groups of 64

    // staging: thread t stages 16B chunk; round r covers rows r*64..r*64+63.
    // LDS chunk (row, p) holds source chunk p ^ (row & 7)  -- XOR swizzle.
    const int srow = t >> 3;                               // 0..63
    const int scol = ((t & 7) ^ (srow & 7)) * 8;
    const unsigned short* Ag = A + (size_t)(bm * 128 + srow) * K + scol;
    const size_t r64K = (size_t)64 * K;

    const int fl = lane & 15;
    const int g = lane >> 4;
    const int s7 = fl & 7;

    // LDS read addresses (bytes): row*(64*2) + ((chunk ^ s7) * 8)*2
    const unsigned ldsA = (unsigned)(size_t)(__attribute__((address_space(3))) unsigned short*)&As[0][0];
    const unsigned rA0 = ldsA + (unsigned)((wm + fl) * 128 + ((g ^ s7) * 16));        // ks0 chunks
    const unsigned rA1 = ldsA + (unsigned)((wm + fl) * 128 + (((4 + g) ^ s7) * 16));  // ks1 chunks

    // B fragment pointers: col = bn*256 + wn + j*16 + fl, k-chunk g*8.
    const unsigned short* pb0 = Bmat + (size_t)(bn * 256 + wn + 0 * 16 + fl) * K + g * 8;
    const unsigned short* pb1 = Bmat + (size_t)(bn * 256 + wn + 1 * 16 + fl) * K + g * 8;
    const unsigned short* pb2 = Bmat + (size_t)(bn * 256 + wn + 2 * 16 + fl) * K + g * 8;
    const unsigned short* pb3 = Bmat + (size_t)(bn * 256 + wn + 3 * 16 + fl) * K + g * 8;

    floatx4 acc[4][4];
    #pragma unroll
    for (int i = 0; i < 4; ++i)
        #pragma unroll
        for (int j = 0; j < 4; ++j) {
            acc[i][j][0] = 0.f; acc[i][j][1] = 0.f;
            acc[i][j][2] = 0.f; acc[i][j][3] = 0.f;
        }

    auto stg = [&](int buf, int rnd, int tile) {
        const unsigned short* s = Ag + (size_t)rnd * r64K + (size_t)tile * 64;
        async_cp16(s, &As[buf][rnd * 4096 + t * 8]);
    };

    const int NT = K >> 6;   // 16 or 32 (even)

    short8 bA[8], bB[8];

    // prologue: b(0) (8 loads), A(0) (2), A(1) (2); wait all but A(1).
    bA[0] = gload128<0>(pb0);  bA[1] = gload128<0>(pb1);
    bA[2] = gload128<0>(pb2);  bA[3] = gload128<0>(pb3);
    bA[4] = gload128<64>(pb0); bA[5] = gload128<64>(pb1);
    bA[6] = gload128<64>(pb2); bA[7] = gload128<64>(pb3);
    stg(0, 0, 0); stg(0, 1, 0);
    stg(1, 0, 1); stg(1, 1, 1);
    asm volatile("s_waitcnt vmcnt(2)" ::: "memory");
    asm volatile("s_barrier" ::: "memory");

    // Per tile tt (R = tt&1):
    //  ph1: 8 ds_read (all a-frags, both ks) | issue b(tt+1) s0 | MFMA ks0 j0,j1
    //  ph2: issue b(tt+1) s1 | barrier (all As[R] reads complete) | MFMA ks0 j2,j3
    //  ph3: stage A(tt+2) rnd0 -> As[R] | MFMA ks1 j0,j1
    //  ph4: stage A(tt+2) rnd1 -> As[R] | MFMA ks1 j2,j3 | vmcnt(2) | barrier
    // vmcnt(2): drains A(tt+1)(2, issued tt-1) + b(tt+1)(8); keeps A(tt+2)(2).
#define FFN_TILE(TT, R, CURB, NXTB)                                            \
    do {                                                                       \
        const bool p1 = (TT) + 1 < NT;                                         \
        const bool p2 = (TT) + 2 < NT;                                         \
        short8 a0k0 = ds_read128<0 * 2048 + (R) * 16384>(rA0);                 \
        short8 a1k0 = ds_read128<1 * 2048 + (R) * 16384>(rA0);                 \
        short8 a2k0 = ds_read128<2 * 2048 + (R) * 16384>(rA0);                 \
        short8 a3k0 = ds_read128<3 * 2048 + (R) * 16384>(rA0);                 \
        short8 a0k1 = ds_read128<0 * 2048 + (R) * 16384>(rA1);                 \
        short8 a1k1 = ds_read128<1 * 2048 + (R) * 16384>(rA1);                 \
        short8 a2k1 = ds_read128<2 * 2048 + (R) * 16384>(rA1);                 \
        short8 a3k1 = ds_read128<3 * 2048 + (R) * 16384>(rA1);                 \
        if (p1) {                                                              \
            NXTB[0] = gload128<((R) + 1) * 128 + 0>(pb0);                      \
            NXTB[1] = gload128<((R) + 1) * 128 + 0>(pb1);                      \
            NXTB[2] = gload128<((R) + 1) * 128 + 0>(pb2);                      \
            NXTB[3] = gload128<((R) + 1) * 128 + 0>(pb3);                      \
        }                                                                      \
        asm volatile("s_waitcnt lgkmcnt(0)" ::: "memory");                     \
        __builtin_amdgcn_sched_barrier(0);                                     \
        __builtin_amdgcn_s_setprio(1);                                         \
        acc[0][0] = mfma16(a0k0, CURB[0], acc[0][0]);                          \
        acc[1][0] = mfma16(a1k0, CURB[0], acc[1][0]);                          \
        acc[2][0] = mfma16(a2k0, CURB[0], acc[2][0]);                          \
        acc[3][0] = mfma16(a3k0, CURB[0], acc[3][0]);                          \
        acc[0][1] = mfma16(a0k0, CURB[1], acc[0][1]);                          \
        acc[1][1] = mfma16(a1k0, CURB[1], acc[1][1]);                          \
        acc[2][1] = mfma16(a2k0, CURB[1], acc[2][1]);                          \
        acc[3][1] = mfma16(a3k0, CURB[1], acc[3][1]);                          \
        __builtin_amdgcn_s_setprio(0);                                         \
        if (p1) {                                                              \
            NXTB[4] = gload128<((R) + 1) * 128 + 64>(pb0);                     \
            NXTB[5] = gload128<((R) + 1) * 128 + 64>(pb1);                     \
            NXTB[6] = gload128<((R) + 1) * 128 + 64>(pb2);                     \
            NXTB[7] = gload128<((R) + 1) * 128 + 64>(pb3);                     \
        }                                                                      \
        asm volatile("s_barrier" ::: "memory");                                \
        __builtin_amdgcn_s_setprio(1);                                         \
        acc[0][2] = mfma16(a0k0, CURB[2], acc[0][2]);                          \
        acc[1][2] = mfma16(a1k0, CURB[2], acc[1][2]);                          \
        acc[2][2] = mfma16(a2k0, CURB[2], acc[2][2]);                          \
        acc[3][2] = mfma16(a3k0, CURB[2], acc[3][2]);                          \
        acc[0][3] = mfma16(a0k0, CURB[3], acc[0][3]);                          \
        acc[1][3] = mfma16(a1k0, CURB[3], acc[1][3]);                          \
        acc[2][3] = mfma16(a2k0, CURB[3], acc[2][3]);                          \
        acc[3][3] = mfma16(a3k0, CURB[3], acc[3][3]);                          \
        __builtin_amdgcn_s_setprio(0);                                         \
        if (p2) stg((R), 0, (TT) + 2);                                         \
        __builtin_amdgcn_s_setprio(1);                                         \
        acc[0][0] = mfma16(a0k1, CURB[4], acc[0][0]);                          \
        acc[1][0] = mfma16(a1k1, CURB[4], acc[1][0]);                          \
        acc[2][0] = mfma16(a2k1, CURB[4], acc[2][0]);                          \
        acc[3][0] = mfma16(a3k1, CURB[4], acc[3][0]);                          \
        acc[0][1] = mfma16(a0k1, CURB[5], acc[0][1]);                          \
        acc[1][1] = mfma16(a1k1, CURB[5], acc[1][1]);                          \
        acc[2][1] = mfma16(a2k1, CURB[5], acc[2][1]);                          \
        acc[3][1] = mfma16(a3k1, CURB[5], acc[3][1]);                          \
        __builtin_amdgcn_s_setprio(0);                                         \
        if (p2) stg((R), 1, (TT) + 2);                                         \
        __builtin_amdgcn_s_setprio(1);                                         \
        acc[0][2] = mfma16(a0k1, CURB[6], acc[0][2]);                          \
        acc[1][2] = mfma16(a1k1, CURB[6], acc[1][2]);                          \
        acc[2][2] = mfma16(a2k1, CURB[6], acc[2][2]);                          \
        acc[3][2] = mfma16(a3k1, CURB[6], acc[3][2]);                          \
        acc[0][3] = mfma16(a0k1, CURB[7], acc[0][3]);                          \
        acc[1][3] = mfma16(a1k1, CURB[7], acc[1][3]);                          \
        acc[2][3] = mfma16(a2k1, CURB[7], acc[2][3]);                          \
        acc[3][3] = mfma16(a3k1, CURB[7], acc[3][3]);                          \
        __builtin_amdgcn_s_setprio(0);                                         \
        if (p2) asm volatile("s_waitcnt vmcnt(2)" ::: "memory");               \
        else    asm volatile("s_waitcnt vmcnt(0)" ::: "memory");               \
        __builtin_amdgcn_sched_barrier(0);                                     \
        asm volatile("s_barrier" ::: "memory");                                \
    } while (0)

    for (int tt = 0; tt < NT; tt += 2) {
        FFN_TILE(tt,     0, bA, bB);
        FFN_TILE(tt + 1, 1, bB, bA);
        pb0 += 128; pb1 += 128; pb2 += 128; pb3 += 128;   // advance one pair (256 B)
    }
#undef FFN_TILE

    const int r0 = g * 4;
    #pragma unroll
    for (int j = 0; j < 4; ++j) {
        const int gcol = bn * 256 + wn + j * 16 + fl;
        float bval = 0.f;
        if (EPI != EPI_NONE) bval = bf2f(bias[gcol]);
        #pragma unroll
        for (int i = 0; i < 4; ++i) {
            const int growb = bm * 128 + wm + i * 16 + r0;
            #pragma unroll
            for (int r = 0; r < 4; ++r) {
                const size_t idx = (size_t)(growb + r) * N + gcol;
                float v = acc[i][j][r];
                if (EPI == EPI_NONE) {
                    C[idx] = f2bf(v);
                } else if (EPI == EPI_BIAS_RELU) {
                    v += bval;
                    v = v > 0.f ? v : 0.f;
                    C[idx] = f2bf(v);
                } else {
                    float nh = hf[idx] + v + bval;
                    hf[idx] = nh;
                    hb[idx] = f2bf(nh);
                }
            }
        }
    }
}

// MFMA flash attention (validated round 4). blockIdx = pair*4 + qquarter.
__global__ __launch_bounds__(128) void attn_mfma(
    const unsigned short* __restrict__ Q,
    const unsigned short* __restrict__ Kx,
    const unsigned short* __restrict__ Vx,
    const float* __restrict__ maskf,
    unsigned short* __restrict__ Out)
{
    __shared__ __align__(16) unsigned short Vt[16 * 520];
    __shared__ __align__(16) unsigned short Pb[2][64 * 40];
    __shared__ float Ms[512];
    __shared__ float cnt_s;

    const int t = threadIdx.x;
    const int lane = t & 63;
    const int wave = t >> 6;
    const int p = blockIdx.x >> 2;
    const int qq = blockIdx.x & 3;
    const int b2 = p & 31;
    const int h2 = p >> 5;
    const int fm = lane & 15;
    const int g = lane >> 4;

    const unsigned short* Qg = Q + (size_t)p * 8192;
    const unsigned short* Kg = Kx + (size_t)p * 8192;
    const unsigned short* Vg = Vx + (size_t)p * 8192;

    #pragma unroll
    for (int rr = 0; rr < 4; ++rr) {
        const int row = t * 4 + rr;
        short8 v0 = *(const short8*)&Vg[row * 16];
        short8 v1 = *(const short8*)&Vg[row * 16 + 8];
        #pragma unroll
        for (int d = 0; d < 8; ++d) Vt[d * 520 + row] = (unsigned short)v0[d];
        #pragma unroll
        for (int d = 0; d < 8; ++d) Vt[(d + 8) * 520 + row] = (unsigned short)v1[d];
    }
    if (t == 0) cnt_s = 0.f;
    __syncthreads();
    float pc = 0.f;
    #pragma unroll
    for (int it = 0; it < 4; ++it) {
        int i = it * 128 + t;
        float mv = maskf[b2 * 512 + i];
        Ms[i] = mv; pc += mv;
    }
    atomicAdd(&cnt_s, pc);
    __syncthreads();
    const float cnt = cnt_s;

    const int qbase = qq * 128 + wave * 64;
    short8 qf[4];
    #pragma unroll
    for (int i = 0; i < 4; ++i) {
        short8 z = {0,0,0,0,0,0,0,0};
        if (g < 2) z = *(const short8*)&Qg[(qbase + i * 16 + fm) * 16 + g * 8];
        qf[i] = z;
    }

    float m_[4][4], l_[4][4];
    floatx4 O[4];
    #pragma unroll
    for (int i = 0; i < 4; ++i) {
        #pragma unroll
        for (int r = 0; r < 4; ++r) { m_[i][r] = -1e30f; l_[i][r] = 0.f; }
        O[i][0] = 0.f; O[i][1] = 0.f; O[i][2] = 0.f; O[i][3] = 0.f;
    }

    unsigned short* Pw = &Pb[wave][0];

    for (int kb = 0; kb < 512; kb += 32) {
        short8 kf0 = {0,0,0,0,0,0,0,0}, kf1 = {0,0,0,0,0,0,0,0};
        if (g < 2) {
            kf0 = *(const short8*)&Kg[(kb + fm) * 16 + g * 8];
            kf1 = *(const short8*)&Kg[(kb + 16 + fm) * 16 + g * 8];
        }
        const float msk0 = Ms[kb + fm];
        const float msk1 = Ms[kb + 16 + fm];

        floatx4 zero4 = {0.f, 0.f, 0.f, 0.f};
        floatx4 s0[4], s1[4];
        #pragma unroll
        for (int i = 0; i < 4; ++i) {
            s0[i] = __builtin_amdgcn_mfma_f32_16x16x32_bf16(qf[i], kf0, zero4, 0, 0, 0);
            s1[i] = __builtin_amdgcn_mfma_f32_16x16x32_bf16(qf[i], kf1, zero4, 0, 0, 0);
        }

        #pragma unroll
        for (int i = 0; i < 4; ++i) {
            #pragma unroll
            for (int r = 0; r < 4; ++r) {
                float a0 = (msk0 != 0.f) ? -1e30f : s0[i][r] * NORM_;
                float a1 = (msk1 != 0.f) ? -1e30f : s1[i][r] * NORM_;
                float mx = fmaxf(a0, a1);
                mx = fmaxf(mx, __shfl_xor(mx, 1));
                mx = fmaxf(mx, __shfl_xor(mx, 2));
                mx = fmaxf(mx, __shfl_xor(mx, 4));
                mx = fmaxf(mx, __shfl_xor(mx, 8));
                const float mo = m_[i][r];
                const float mn = fmaxf(mo, mx);
                const float alpha = __expf(mo - mn);
                float w0 = (msk0 != 0.f) ? 0.f : __expf(a0 - mn);
                float w1 = (msk1 != 0.f) ? 0.f : __expf(a1 - mn);
                float rs = w0 + w1;
                rs += __shfl_xor(rs, 1);
                rs += __shfl_xor(rs, 2);
                rs += __shfl_xor(rs, 4);
                rs += __shfl_xor(rs, 8);
                l_[i][r] = l_[i][r] * alpha + rs;
                m_[i][r] = mn;
                O[i][r] *= alpha;
                const int qloc = i * 16 + g * 4 + r;
                Pw[qloc * 40 + fm] = f2bf(w0);
                Pw[qloc * 40 + 16 + fm] = f2bf(w1);
            }
        }
        asm volatile("s_waitcnt lgkmcnt(0)" ::: "memory");

        short8 vtf = *(const short8*)&Vt[fm * 520 + kb + g * 8];
        #pragma unroll
        for (int i = 0; i < 4; ++i) {
            short8 pf = *(const short8*)&Pw[(i * 16 + fm) * 40 + g * 8];
            O[i] = __builtin_amdgcn_mfma_f32_16x16x32_bf16(pf, vtf, O[i], 0, 0, 0);
        }
    }

    #pragma unroll
    for (int i = 0; i < 4; ++i) {
        #pragma unroll
        for (int r = 0; r < 4; ++r) {
            const float M = fmaxf(m_[i][r], -30.f);
            const float adj = __expf(m_[i][r] - M);
            const float lf = l_[i][r] * adj + cnt * __expf(-30.f - M);
            const float oval = O[i][r] * adj / lf;
            const int n = qbase + i * 16 + g * 4 + r;
            Out[((size_t)(b2 * 512 + n)) * 128 + h2 * 16 + fm] = f2bf(oval);
        }
    }
}

__global__ __launch_bounds__(256) void write_h(const float* __restrict__ hf,
                                               void* __restrict__ out,
                                               const int* __restrict__ flag)
{
    const size_t i = ((size_t)blockIdx.x * 256 + threadIdx.x) * 4;
    floatx4 v = *(const floatx4*)&hf[i];
    if (*flag) {
        *(floatx4*)((float*)out + i) = v;
    } else {
        unsigned int p0 = (unsigned int)f2bf(v[0]) | ((unsigned int)f2bf(v[1]) << 16);
        unsigned int p1 = (unsigned int)f2bf(v[2]) | ((unsigned int)f2bf(v[3]) << 16);
        unsigned int* o = (unsigned int*)((unsigned short*)out + i);
        o[0] = p0; o[1] = p1;
    }
}

__global__ __launch_bounds__(256) void mean_kernel(const float* __restrict__ hf,
                                                   void* __restrict__ out,
                                                   const int* __restrict__ flag)
{
    const int b = blockIdx.x >> 2;
    const int e = ((blockIdx.x & 3) * 256) + threadIdx.x;
    float s = 0.f;
    for (int n = 0; n < 512; ++n) s += hf[((size_t)(b * 512 + n)) * 1024 + e];
    s *= (1.0f / 512.0f);
    const size_t off = (size_t)16384 * 1024 + b * 1024 + e;
    if (*flag) ((float*)out)[off] = s;
    else       ((unsigned short*)out)[off] = f2bf(s);
}

extern "C" void kernel_launch(void* const* d_in, const int* in_sizes, int n_in,
                              void* d_out, int out_size, void* d_ws, size_t ws_size,
                              hipStream_t stream)
{
    const void* x  = d_in[0];
    const unsigned int* mask = (const unsigned int*)d_in[1];

    char* ws = (char*)d_ws;
    float* hf = (float*)ws;                     ws += (size_t)16384 * 1024 * 4;   // 64 MB
    unsigned short* hb = (unsigned short*)ws;   ws += (size_t)16384 * 1024 * 2;   // 32 MB
    char* shared_rg = ws;                       ws += (size_t)16384 * 2048 * 2;   // 64 MB
    unsigned short* act = (unsigned short*)shared_rg;
    unsigned short* q  = (unsigned short*)shared_rg;
    unsigned short* k  = q + (size_t)16384 * 128;
    unsigned short* v  = k + (size_t)16384 * 128;
    unsigned short* ao = v + (size_t)16384 * 128;
    unsigned short* cWq = (unsigned short*)ws;  ws += (size_t)393216 * 2;
    unsigned short* cWk = (unsigned short*)ws;  ws += (size_t)393216 * 2;
    unsigned short* cWv = (unsigned short*)ws;  ws += (size_t)393216 * 2;
    unsigned short* cWo = (unsigned short*)ws;  ws += (size_t)393216 * 2;
    unsigned short* cbo = (unsigned short*)ws;  ws += (size_t)3072 * 2;
    unsigned short* cW1 = (unsigned short*)ws;  ws += (size_t)6291456 * 2;
    unsigned short* cb1 = (unsigned short*)ws;  ws += (size_t)6144 * 2;
    unsigned short* cW2 = (unsigned short*)ws;  ws += (size_t)6291456 * 2;
    unsigned short* cb2 = (unsigned short*)ws;  ws += (size_t)3072 * 2;
    float* maskf = (float*)ws;                  ws += (size_t)16384 * 4;
    int* flag = (int*)ws;                       ws += 256;

    detect_dtype<<<1, 256, 0, stream>>>((const unsigned int*)x, flag);

    auto conv = [&](const void* s, unsigned short* d, int n) {
        conv_to_bf16<<<(n / 8 + 255) / 256, 256, 0, stream>>>(s, d, n, flag);
    };
    conv(d_in[2], cWq, 393216);
    conv(d_in[3], cWk, 393216);
    conv(d_in[4], cWv, 393216);
    conv(d_in[5], cWo, 393216);
    conv(d_in[6], cbo, 3072);
    conv(d_in[7], cW1, 6291456);
    conv(d_in[8], cb1, 6144);
    conv(d_in[9], cW2, 6291456);
    conv(d_in[10], cb2, 3072);

    mask_expand<<<64, 256, 0, stream>>>(mask, maskf);
    init_h<<<8192, 256, 0, stream>>>(x, hf, hb, flag);

    for (int l = 0; l < 3; ++l) {
        const unsigned short* wq  = cWq + (size_t)l * 131072;
        const unsigned short* wk  = cWk + (size_t)l * 131072;
        const unsigned short* wv  = cWv + (size_t)l * 131072;
        const unsigned short* wo  = cWo + (size_t)l * 131072;
        const unsigned short* bol = cbo + (size_t)l * 1024;
        const unsigned short* w1  = cW1 + (size_t)l * 2097152;
        const unsigned short* b1l = cb1 + (size_t)l * 2048;
        const unsigned short* w2  = cW2 + (size_t)l * 2097152;
        const unsigned short* b2l = cb2 + (size_t)l * 1024;

        gemm_bt<EPI_NONE><<<dim3(128, 1, 3), 256, 0, stream>>>(
            hb, wq, wk, wv, q, k, v, nullptr, nullptr, nullptr, 128, 1024);
        attn_mfma<<<1024, 128, 0, stream>>>(q, k, v, maskf, ao);
        gemm_bt<EPI_BIAS_RES><<<dim3(128, 8, 1), 256, 0, stream>>>(
            ao, wo, wo, wo, nullptr, nullptr, nullptr, bol, hf, hb, 1024, 128);
        gemm_ffn<EPI_BIAS_RELU><<<dim3(128, 8, 1), 512, 0, stream>>>(
            hb, w1, act, b1l, nullptr, nullptr, 2048, 1024);
        gemm_ffn<EPI_BIAS_RES><<<dim3(128, 4, 1), 512, 0, stream>>>(
            act, w2, nullptr, b2l, hf, hb, 1024, 2048);
    }

    write_h<<<16384, 256, 0, stream>>>(hf, d_out, flag);
    mean_kernel<<<128, 256, 0, stream>>>(hf, d_out, flag);
}

// Round 7
// 1236.689 us; speedup vs baseline: 1.3312x; 1.3312x over previous
//
#include <hip/hip_runtime.h>
#include <stdint.h>

// Problem: B=32, N=512, E=1024, H=8, L=3, FF=2048, KD=128, DK=16
// Transport dtype (f32 vs bf16) detected on device; compute bf16 MFMA + f32 master h.
// FFN1 (N=2048,K=1024): gemm256_bt (256^2 8-phase, measured ~79us).
// FFN2 (N=1024,K=2048): gemm_bt 128^2 (4 blocks/CU overlaps the fat residual
// epilogue; gemm256_bt at 1 block/CU serializes it -> 137us vs 116us measured).

typedef __attribute__((ext_vector_type(8))) short short8;
typedef __attribute__((ext_vector_type(4))) float floatx4;

#define NORM_ 0.08838834764831845f   // 1/sqrt(128)

__device__ __forceinline__ float bf2f(unsigned short u) {
    union { unsigned int i; float f; } x; x.i = ((unsigned int)u) << 16; return x.f;
}
__device__ __forceinline__ unsigned short f2bf(float f) {  // RNE
    union { float f; unsigned int i; } x; x.f = f;
    unsigned int u = x.i;
    u += 0x7FFFu + ((u >> 16) & 1u);
    return (unsigned short)(u >> 16);
}
__device__ __forceinline__ void async_cp16(const void* g, void* l) {
    __builtin_amdgcn_global_load_lds((const __attribute__((address_space(1))) void*)g,
                                     (__attribute__((address_space(3))) void*)l, 16, 0, 0);
}
__device__ __forceinline__ floatx4 mfma16(short8 a, short8 b, floatx4 c) {
    return __builtin_amdgcn_mfma_f32_16x16x32_bf16(a, b, c, 0, 0, 0);
}

// ---- transport dtype detection -------------------------------------------
__global__ __launch_bounds__(256) void detect_dtype(const unsigned int* __restrict__ x,
                                                    int* __restrict__ flag)
{
    __shared__ int good, bad;
    if (threadIdx.x == 0) { good = 0; bad = 0; }
    __syncthreads();
    int g = 0, b = 0;
    for (int i = threadIdx.x; i < 4096; i += 256) {
        unsigned int lo = x[i] & 0xFFFFu;
        if (lo != 0u) {
            unsigned int e = (lo >> 7) & 0xFFu;
            if (e >= 90u && e <= 145u) ++g; else ++b;
        }
    }
    atomicAdd(&good, g); atomicAdd(&bad, b);
    __syncthreads();
    if (threadIdx.x == 0) *flag = (bad > good) ? 1 : 0;   // 1 = f32 transport
}

__global__ __launch_bounds__(256) void conv_to_bf16(const void* __restrict__ src,
                                                    unsigned short* __restrict__ dst,
                                                    int n, const int* __restrict__ flag)
{
    const int i = (blockIdx.x * 256 + threadIdx.x) * 8;
    if (i >= n) return;
    if (*flag) {
        const float* s = (const float*)src + i;
        floatx4 a = *(const floatx4*)s;
        floatx4 b = *(const floatx4*)(s + 4);
        short8 o;
        o[0] = (short)f2bf(a[0]); o[1] = (short)f2bf(a[1]);
        o[2] = (short)f2bf(a[2]); o[3] = (short)f2bf(a[3]);
        o[4] = (short)f2bf(b[0]); o[5] = (short)f2bf(b[1]);
        o[6] = (short)f2bf(b[2]); o[7] = (short)f2bf(b[3]);
        *(short8*)(dst + i) = o;
    } else {
        *(short8*)(dst + i) = *(const short8*)((const unsigned short*)src + i);
    }
}

__global__ __launch_bounds__(256) void init_h(const void* __restrict__ x,
                                              float* __restrict__ hf,
                                              unsigned short* __restrict__ hb,
                                              const int* __restrict__ flag)
{
    const size_t i = ((size_t)blockIdx.x * 256 + threadIdx.x) * 8;
    if (*flag) {
        const float* s = (const float*)x + i;
        floatx4 a = *(const floatx4*)s;
        floatx4 b = *(const floatx4*)(s + 4);
        short8 o;
        o[0] = (short)f2bf(a[0]); o[1] = (short)f2bf(a[1]);
        o[2] = (short)f2bf(a[2]); o[3] = (short)f2bf(a[3]);
        o[4] = (short)f2bf(b[0]); o[5] = (short)f2bf(b[1]);
        o[6] = (short)f2bf(b[2]); o[7] = (short)f2bf(b[3]);
        *(short8*)(hb + i) = o;
        *(floatx4*)(hf + i) = a;
        *(floatx4*)(hf + i + 4) = b;
    } else {
        short8 v = *(const short8*)((const unsigned short*)x + i);
        *(short8*)(hb + i) = v;
        #pragma unroll
        for (int e = 0; e < 8; ++e) hf[i + e] = bf2f((unsigned short)v[e]);
    }
}

__global__ __launch_bounds__(256) void mask_expand(const unsigned int* __restrict__ mraw,
                                                   float* __restrict__ maskf)
{
    __shared__ unsigned int r[4];
    if (threadIdx.x < 4) r[threadIdx.x] = 0;
    __syncthreads();
    unsigned int gt1 = 0, badb = 0, badh = 0, lo3f = 0;
    for (int i = threadIdx.x; i < 4096; i += 256) {
        unsigned int w = mraw[i];
        if (w > 1u) gt1 = 1;
        if (w & 0xFEFEFEFEu) badb = 1;
        unsigned int lo = w & 0xFFFFu, hi = w >> 16;
        if ((lo != 0u && lo != 0x3F80u) || (hi != 0u && hi != 0x3F80u)) badh = 1;
        if (lo == 0x3F80u) lo3f = 1;
    }
    if (gt1) atomicOr(&r[0], 1u);
    if (badb) atomicOr(&r[1], 1u);
    if (badh) atomicOr(&r[2], 1u);
    if (lo3f) atomicOr(&r[3], 1u);
    __syncthreads();
    int cls;
    if (!r[0]) cls = 0;
    else if (!r[1]) cls = 1;
    else if (!r[2]) cls = r[3] ? 2 : 3;
    else cls = 0;

    const int gid = blockIdx.x * 256 + threadIdx.x;
    bool m;
    if (cls == 0)      m = ((const int*)mraw)[gid] != 0;
    else if (cls == 1) m = ((const unsigned char*)mraw)[gid] != 0;
    else if (cls == 2) m = ((const unsigned short*)mraw)[gid] != 0;
    else               m = mraw[gid] != 0u;
    maskf[gid] = m ? 1.0f : 0.0f;
}

enum { EPI_NONE = 0, EPI_BIAS_RELU = 1, EPI_BIAS_RES = 2 };

// ---------------------------------------------------------------------------
// 128x128 tile kernel (proven) — QKV (N=128), Wo (K=128), FFN2 (4 blk/CU).
// ---------------------------------------------------------------------------
template<int EPI>
__global__ __launch_bounds__(256) void gemm_bt(
    const unsigned short* __restrict__ A,
    const unsigned short* __restrict__ Bq,
    const unsigned short* __restrict__ Bk,
    const unsigned short* __restrict__ Bv,
    unsigned short* __restrict__ Cq,
    unsigned short* __restrict__ Ck,
    unsigned short* __restrict__ Cv,
    const unsigned short* __restrict__ bias,
    float* __restrict__ hf,
    unsigned short* __restrict__ hb,
    int N, int K)
{
    constexpr int BK = 64;
    __shared__ __align__(16) unsigned short As[2][128 * BK];   // 2 x 16 KB
    __shared__ __align__(16) unsigned short Bs[2][128 * BK];   // 2 x 16 KB

    const int t = threadIdx.x;
    const int lane = t & 63;
    const int wave = t >> 6;
    const int bm = blockIdx.x;
    const int bn = blockIdx.y;
    const int bz = blockIdx.z;

    const unsigned short* Bmat = (bz == 0) ? Bq : ((bz == 1) ? Bk : Bv);
    unsigned short* C = (bz == 0) ? Cq : ((bz == 1) ? Ck : Cv);

    const int wm = (wave >> 1) * 64;
    const int wn = (wave & 1) * 64;

    const int srow = t >> 3;                               // 0..31
    const int scol = (((t & 7) ^ ((t >> 3) & 7)) * 8);     // swizzled source col
    const unsigned short* Ag = A + (size_t)(bm * 128 + srow) * K + scol;
    const unsigned short* Bg = Bmat + (size_t)(bn * 128 + srow) * K + scol;
    const size_t gstep = (size_t)32 * K;                   // 32 rows per round

    const int fl = lane & 15;
    const int g = lane >> 4;
    const int s7 = fl & 7;
    const int swz0 = (g ^ s7) * 8;          // ks = 0 chunk
    const int swz1 = ((g + 4) ^ s7) * 8;    // ks = 32 chunk
    int aoff[4], boff[4];
    #pragma unroll
    for (int i = 0; i < 4; ++i) {
        aoff[i] = (wm + i * 16 + fl) * BK;
        boff[i] = (wn + i * 16 + fl) * BK;
    }

    floatx4 acc[4][4];
    #pragma unroll
    for (int i = 0; i < 4; ++i)
        #pragma unroll
        for (int j = 0; j < 4; ++j) {
            acc[i][j][0] = 0.f; acc[i][j][1] = 0.f;
            acc[i][j][2] = 0.f; acc[i][j][3] = 0.f;
        }

    const int NT = K / BK;

    #pragma unroll
    for (int r = 0; r < 4; ++r) {
        async_cp16(Ag + r * gstep, &As[0][t * 8 + r * 2048]);
        async_cp16(Bg + r * gstep, &Bs[0][t * 8 + r * 2048]);
    }

    for (int it = 0; it < NT; ++it) {
        const int cur = it & 1;
        if (it + 1 < NT) {
            const int nxt = cur ^ 1;
            const size_t koff = (size_t)(it + 1) * BK;
            #pragma unroll
            for (int r = 0; r < 4; ++r) {
                async_cp16(Ag + koff + r * gstep, &As[nxt][t * 8 + r * 2048]);
                async_cp16(Bg + koff + r * gstep, &Bs[nxt][t * 8 + r * 2048]);
            }
            asm volatile("s_waitcnt vmcnt(8)" ::: "memory");
        } else {
            asm volatile("s_waitcnt vmcnt(0)" ::: "memory");
        }
        asm volatile("s_barrier" ::: "memory");

        #pragma unroll
        for (int ks = 0; ks < 2; ++ks) {
            const int sw = ks ? swz1 : swz0;
            short8 af[4], bfr[4];
            #pragma unroll
            for (int i = 0; i < 4; ++i) af[i] = *(const short8*)&As[cur][aoff[i] + sw];
            #pragma unroll
            for (int j = 0; j < 4; ++j) bfr[j] = *(const short8*)&Bs[cur][boff[j] + sw];
            #pragma unroll
            for (int i = 0; i < 4; ++i)
                #pragma unroll
                for (int j = 0; j < 4; ++j)
                    acc[i][j] = __builtin_amdgcn_mfma_f32_16x16x32_bf16(af[i], bfr[j], acc[i][j], 0, 0, 0);
        }
        if (it + 1 < NT)
            asm volatile("s_barrier" ::: "memory");
    }

    const int r0 = (lane >> 4) * 4;
    #pragma unroll
    for (int j = 0; j < 4; ++j) {
        const int gcol = bn * 128 + wn + j * 16 + fl;
        float bval = 0.f;
        if (EPI != EPI_NONE) bval = bf2f(bias[gcol]);
        #pragma unroll
        for (int i = 0; i < 4; ++i) {
            const int growb = bm * 128 + wm + i * 16 + r0;
            #pragma unroll
            for (int r = 0; r < 4; ++r) {
                const size_t idx = (size_t)(growb + r) * N + gcol;
                float v = acc[i][j][r];
                if (EPI == EPI_NONE) {
                    C[idx] = f2bf(v);
                } else if (EPI == EPI_BIAS_RELU) {
                    v += bval;
                    v = v > 0.f ? v : 0.f;
                    C[idx] = f2bf(v);
                } else {
                    float nh = hf[idx] + v + bval;
                    hf[idx] = nh;
                    hb[idx] = f2bf(nh);
                }
            }
        }
    }
}

// ---------------------------------------------------------------------------
// 256x256 tile, BK=64, 512 threads (8 waves, 2M x 4N), 8-phase interleaved
// schedule with counted vmcnt. Measured ~79us on FFN1 (870 TF).
// ---------------------------------------------------------------------------
template<int EPI>
__global__ __launch_bounds__(512) void gemm256_bt(
    const unsigned short* __restrict__ A,
    const unsigned short* __restrict__ Bmat,
    unsigned short* __restrict__ C,
    const unsigned short* __restrict__ bias,
    float* __restrict__ hf,
    unsigned short* __restrict__ hb,
    int N, int K)
{
    __shared__ __align__(16) unsigned short As[2][16384];   // 2 x 256 x 64 (two 128-row halves)
    __shared__ __align__(16) unsigned short Bs[2][16384];

    const int t = threadIdx.x;           // 0..511
    const int lane = t & 63;
    const int wave = t >> 6;             // 0..7
    const int bm = blockIdx.x;
    const int bn = blockIdx.y;

    const int wm = (wave >> 2) * 128;    // waves 0-3 -> rows 0..127, 4-7 -> 128..255
    const int wn = (wave & 3) * 64;

    const int srow = t >> 3;                               // 0..63
    const int scol = ((t & 7) ^ (srow & 7)) * 8;
    const unsigned short* Ag = A + (size_t)(bm * 256 + srow) * K + scol;
    const unsigned short* Bg = Bmat + (size_t)(bn * 256 + srow) * K + scol;
    const size_t rows64 = (size_t)64 * K;

    const int fl = lane & 15;
    const int g = lane >> 4;
    const int s7 = fl & 7;
    const int c0 = (g ^ s7) * 8;           // ks=0 chunk offset (ushorts)
    const int c1 = ((4 + g) ^ s7) * 8;     // ks=1
    const int abase = (wm + fl) * 64;
    const int bbase = (wn + fl) * 64;

    floatx4 acc[8][4];
    #pragma unroll
    for (int i = 0; i < 8; ++i)
        #pragma unroll
        for (int j = 0; j < 4; ++j) {
            acc[i][j][0] = 0.f; acc[i][j][1] = 0.f;
            acc[i][j][2] = 0.f; acc[i][j][3] = 0.f;
        }

    auto stgA = [&](int buf, int h, size_t koff) {
        const unsigned short* s = Ag + (size_t)(h * 128) * K + koff;
        unsigned short* d = &As[buf][h * 8192 + t * 8];
        async_cp16(s, d);
        async_cp16(s + rows64, d + 4096);
    };
    auto stgB = [&](int buf, int h, size_t koff) {
        const unsigned short* s = Bg + (size_t)(h * 128) * K + koff;
        unsigned short* d = &Bs[buf][h * 8192 + t * 8];
        async_cp16(s, d);
        async_cp16(s + rows64, d + 4096);
    };

    const int NT = K >> 6;

    // prologue: tile0 (4 half-tiles) + A halves of tile1; wait tile0 only.
    stgA(0, 0, 0); stgA(0, 1, 0); stgB(0, 0, 0); stgB(0, 1, 0);
    if (NT > 1) {
        stgA(1, 0, 64); stgA(1, 1, 64);
        asm volatile("s_waitcnt vmcnt(4)" ::: "memory");
    } else {
        asm volatile("s_waitcnt vmcnt(0)" ::: "memory");
    }
    asm volatile("s_barrier" ::: "memory");

    for (int tt = 0; tt < NT; ++tt) {
        const int R = tt & 1;
        const int S = R ^ 1;
        const size_t k1 = (size_t)(tt + 1) << 6;
        const size_t k2 = (size_t)(tt + 2) << 6;
        const bool p1 = (tt + 1 < NT);
        const bool p2 = (tt + 2 < NT);

        short8 a0[8], a1[8], b0[4], b1[4];

        // ---- phase 1 ----
        #pragma unroll
        for (int i = 0; i < 8; ++i) a0[i] = *(const short8*)&As[R][abase + i * 1024 + c0];
        #pragma unroll
        for (int j = 0; j < 4; ++j) b0[j] = *(const short8*)&Bs[R][bbase + j * 1024 + c0];
        if (p1) stgB(S, 0, k1);
        asm volatile("s_barrier" ::: "memory");
        asm volatile("s_waitcnt lgkmcnt(0)" ::: "memory");
        __builtin_amdgcn_s_setprio(1);
        #pragma unroll
        for (int i = 0; i < 8; ++i) {
            acc[i][0] = mfma16(a0[i], b0[0], acc[i][0]);
            acc[i][1] = mfma16(a0[i], b0[1], acc[i][1]);
        }
        __builtin_amdgcn_s_setprio(0);
        asm volatile("s_barrier" ::: "memory");

        // ---- phase 2 ----
        #pragma unroll
        for (int i = 0; i < 8; ++i) a1[i] = *(const short8*)&As[R][abase + i * 1024 + c1];
        #pragma unroll
        for (int j = 0; j < 4; ++j) b1[j] = *(const short8*)&Bs[R][bbase + j * 1024 + c1];
        if (p1) stgB(S, 1, k1);
        asm volatile("s_barrier" ::: "memory");
        asm volatile("s_waitcnt lgkmcnt(0)" ::: "memory");   // all buf-R reads retired
        __builtin_amdgcn_s_setprio(1);
        #pragma unroll
        for (int i = 0; i < 8; ++i) {
            acc[i][2] = mfma16(a0[i], b0[2], acc[i][2]);
            acc[i][3] = mfma16(a0[i], b0[3], acc[i][3]);
        }
        __builtin_amdgcn_s_setprio(0);
        asm volatile("s_barrier" ::: "memory");

        // ---- phase 3 (safe to restage buf R: no further LDS reads this tile) ----
        if (p2) stgA(R, 0, k2);
        asm volatile("s_barrier" ::: "memory");
        __builtin_amdgcn_s_setprio(1);
        #pragma unroll
        for (int i = 0; i < 8; ++i) {
            acc[i][0] = mfma16(a1[i], b1[0], acc[i][0]);
            acc[i][1] = mfma16(a1[i], b1[1], acc[i][1]);
        }
        __builtin_amdgcn_s_setprio(0);
        asm volatile("s_barrier" ::: "memory");

        // ---- phase 4 ----
        if (p2) stgA(R, 1, k2);
        asm volatile("s_barrier" ::: "memory");
        __builtin_amdgcn_s_setprio(1);
        #pragma unroll
        for (int i = 0; i < 8; ++i) {
            acc[i][2] = mfma16(a1[i], b1[2], acc[i][2]);
            acc[i][3] = mfma16(a1[i], b1[3], acc[i][3]);
        }
        __builtin_amdgcn_s_setprio(0);
        if (p2) asm volatile("s_waitcnt vmcnt(4)" ::: "memory");
        else    asm volatile("s_waitcnt vmcnt(0)" ::: "memory");
        asm volatile("s_barrier" ::: "memory");
    }

    const int r0 = g * 4;
    #pragma unroll
    for (int j = 0; j < 4; ++j) {
        const int gcol = bn * 256 + wn + j * 16 + fl;
        float bval = 0.f;
        if (EPI != EPI_NONE) bval = bf2f(bias[gcol]);
        #pragma unroll
        for (int i = 0; i < 8; ++i) {
            const int growb = bm * 256 + wm + i * 16 + r0;
            #pragma unroll
            for (int r = 0; r < 4; ++r) {
                const size_t idx = (size_t)(growb + r) * N + gcol;
                float v = acc[i][j][r];
                if (EPI == EPI_NONE) {
                    C[idx] = f2bf(v);
                } else if (EPI == EPI_BIAS_RELU) {
                    v += bval;
                    v = v > 0.f ? v : 0.f;
                    C[idx] = f2bf(v);
                } else {
                    float nh = hf[idx] + v + bval;
                    hf[idx] = nh;
                    hb[idx] = f2bf(nh);
                }
            }
        }
    }
}

// MFMA flash attention (validated round 4). blockIdx = pair*4 + qquarter.
__global__ __launch_bounds__(128) void attn_mfma(
    const unsigned short* __restrict__ Q,
    const unsigned short* __restrict__ Kx,
    const unsigned short* __restrict__ Vx,
    const float* __restrict__ maskf,
    unsigned short* __restrict__ Out)
{
    __shared__ __align__(16) unsigned short Vt[16 * 520];
    __shared__ __align__(16) unsigned short Pb[2][64 * 40];
    __shared__ float Ms[512];
    __shared__ float cnt_s;

    const int t = threadIdx.x;
    const int lane = t & 63;
    const int wave = t >> 6;
    const int p = blockIdx.x >> 2;
    const int qq = blockIdx.x & 3;
    const int b2 = p & 31;
    const int h2 = p >> 5;
    const int fm = lane & 15;
    const int g = lane >> 4;

    const unsigned short* Qg = Q + (size_t)p * 8192;
    const unsigned short* Kg = Kx + (size_t)p * 8192;
    const unsigned short* Vg = Vx + (size_t)p * 8192;

    #pragma unroll
    for (int rr = 0; rr < 4; ++rr) {
        const int row = t * 4 + rr;
        short8 v0 = *(const short8*)&Vg[row * 16];
        short8 v1 = *(const short8*)&Vg[row * 16 + 8];
        #pragma unroll
        for (int d = 0; d < 8; ++d) Vt[d * 520 + row] = (unsigned short)v0[d];
        #pragma unroll
        for (int d = 0; d < 8; ++d) Vt[(d + 8) * 520 + row] = (unsigned short)v1[d];
    }
    if (t == 0) cnt_s = 0.f;
    __syncthreads();
    float pc = 0.f;
    #pragma unroll
    for (int it = 0; it < 4; ++it) {
        int i = it * 128 + t;
        float mv = maskf[b2 * 512 + i];
        Ms[i] = mv; pc += mv;
    }
    atomicAdd(&cnt_s, pc);
    __syncthreads();
    const float cnt = cnt_s;

    const int qbase = qq * 128 + wave * 64;
    short8 qf[4];
    #pragma unroll
    for (int i = 0; i < 4; ++i) {
        short8 z = {0,0,0,0,0,0,0,0};
        if (g < 2) z = *(const short8*)&Qg[(qbase + i * 16 + fm) * 16 + g * 8];
        qf[i] = z;
    }

    float m_[4][4], l_[4][4];
    floatx4 O[4];
    #pragma unroll
    for (int i = 0; i < 4; ++i) {
        #pragma unroll
        for (int r = 0; r < 4; ++r) { m_[i][r] = -1e30f; l_[i][r] = 0.f; }
        O[i][0] = 0.f; O[i][1] = 0.f; O[i][2] = 0.f; O[i][3] = 0.f;
    }

    unsigned short* Pw = &Pb[wave][0];

    for (int kb = 0; kb < 512; kb += 32) {
        short8 kf0 = {0,0,0,0,0,0,0,0}, kf1 = {0,0,0,0,0,0,0,0};
        if (g < 2) {
            kf0 = *(const short8*)&Kg[(kb + fm) * 16 + g * 8];
            kf1 = *(const short8*)&Kg[(kb + 16 + fm) * 16 + g * 8];
        }
        const float msk0 = Ms[kb + fm];
        const float msk1 = Ms[kb + 16 + fm];

        floatx4 zero4 = {0.f, 0.f, 0.f, 0.f};
        floatx4 s0[4], s1[4];
        #pragma unroll
        for (int i = 0; i < 4; ++i) {
            s0[i] = __builtin_amdgcn_mfma_f32_16x16x32_bf16(qf[i], kf0, zero4, 0, 0, 0);
            s1[i] = __builtin_amdgcn_mfma_f32_16x16x32_bf16(qf[i], kf1, zero4, 0, 0, 0);
        }

        #pragma unroll
        for (int i = 0; i < 4; ++i) {
            #pragma unroll
            for (int r = 0; r < 4; ++r) {
                float a0 = (msk0 != 0.f) ? -1e30f : s0[i][r] * NORM_;
                float a1 = (msk1 != 0.f) ? -1e30f : s1[i][r] * NORM_;
                float mx = fmaxf(a0, a1);
                mx = fmaxf(mx, __shfl_xor(mx, 1));
                mx = fmaxf(mx, __shfl_xor(mx, 2));
                mx = fmaxf(mx, __shfl_xor(mx, 4));
                mx = fmaxf(mx, __shfl_xor(mx, 8));
                const float mo = m_[i][r];
                const float mn = fmaxf(mo, mx);
                const float alpha = __expf(mo - mn);
                float w0 = (msk0 != 0.f) ? 0.f : __expf(a0 - mn);
                float w1 = (msk1 != 0.f) ? 0.f : __expf(a1 - mn);
                float rs = w0 + w1;
                rs += __shfl_xor(rs, 1);
                rs += __shfl_xor(rs, 2);
                rs += __shfl_xor(rs, 4);
                rs += __shfl_xor(rs, 8);
                l_[i][r] = l_[i][r] * alpha + rs;
                m_[i][r] = mn;
                O[i][r] *= alpha;
                const int qloc = i * 16 + g * 4 + r;
                Pw[qloc * 40 + fm] = f2bf(w0);
                Pw[qloc * 40 + 16 + fm] = f2bf(w1);
            }
        }
        asm volatile("s_waitcnt lgkmcnt(0)" ::: "memory");

        short8 vtf = *(const short8*)&Vt[fm * 520 + kb + g * 8];
        #pragma unroll
        for (int i = 0; i < 4; ++i) {
            short8 pf = *(const short8*)&Pw[(i * 16 + fm) * 40 + g * 8];
            O[i] = __builtin_amdgcn_mfma_f32_16x16x32_bf16(pf, vtf, O[i], 0, 0, 0);
        }
    }

    #pragma unroll
    for (int i = 0; i < 4; ++i) {
        #pragma unroll
        for (int r = 0; r < 4; ++r) {
            const float M = fmaxf(m_[i][r], -30.f);
            const float adj = __expf(m_[i][r] - M);
            const float lf = l_[i][r] * adj + cnt * __expf(-30.f - M);
            const float oval = O[i][r] * adj / lf;
            const int n = qbase + i * 16 + g * 4 + r;
            Out[((size_t)(b2 * 512 + n)) * 128 + h2 * 16 + fm] = f2bf(oval);
        }
    }
}

__global__ __launch_bounds__(256) void write_h(const float* __restrict__ hf,
                                               void* __restrict__ out,
                                               const int* __restrict__ flag)
{
    const size_t i = ((size_t)blockIdx.x * 256 + threadIdx.x) * 4;
    floatx4 v = *(const floatx4*)&hf[i];
    if (*flag) {
        *(floatx4*)((float*)out + i) = v;
    } else {
        unsigned int p0 = (unsigned int)f2bf(v[0]) | ((unsigned int)f2bf(v[1]) << 16);
        unsigned int p1 = (unsigned int)f2bf(v[2]) | ((unsigned int)f2bf(v[3]) << 16);
        unsigned int* o = (unsigned int*)((unsigned short*)out + i);
        o[0] = p0; o[1] = p1;
    }
}

__global__ __launch_bounds__(256) void mean_kernel(const float* __restrict__ hf,
                                                   void* __restrict__ out,
                                                   const int* __restrict__ flag)
{
    const int b = blockIdx.x >> 2;
    const int e = ((blockIdx.x & 3) * 256) + threadIdx.x;
    float s = 0.f;
    for (int n = 0; n < 512; ++n) s += hf[((size_t)(b * 512 + n)) * 1024 + e];
    s *= (1.0f / 512.0f);
    const size_t off = (size_t)16384 * 1024 + b * 1024 + e;
    if (*flag) ((float*)out)[off] = s;
    else       ((unsigned short*)out)[off] = f2bf(s);
}

extern "C" void kernel_launch(void* const* d_in, const int* in_sizes, int n_in,
                              void* d_out, int out_size, void* d_ws, size_t ws_size,
                              hipStream_t stream)
{
    const void* x  = d_in[0];
    const unsigned int* mask = (const unsigned int*)d_in[1];

    char* ws = (char*)d_ws;
    float* hf = (float*)ws;                     ws += (size_t)16384 * 1024 * 4;   // 64 MB
    unsigned short* hb = (unsigned short*)ws;   ws += (size_t)16384 * 1024 * 2;   // 32 MB
    char* shared_rg = ws;                       ws += (size_t)16384 * 2048 * 2;   // 64 MB
    unsigned short* act = (unsigned short*)shared_rg;
    unsigned short* q  = (unsigned short*)shared_rg;
    unsigned short* k  = q + (size_t)16384 * 128;
    unsigned short* v  = k + (size_t)16384 * 128;
    unsigned short* ao = v + (size_t)16384 * 128;
    unsigned short* cWq = (unsigned short*)ws;  ws += (size_t)393216 * 2;
    unsigned short* cWk = (unsigned short*)ws;  ws += (size_t)393216 * 2;
    unsigned short* cWv = (unsigned short*)ws;  ws += (size_t)393216 * 2;
    unsigned short* cWo = (unsigned short*)ws;  ws += (size_t)393216 * 2;
    unsigned short* cbo = (unsigned short*)ws;  ws += (size_t)3072 * 2;
    unsigned short* cW1 = (unsigned short*)ws;  ws += (size_t)6291456 * 2;
    unsigned short* cb1 = (unsigned short*)ws;  ws += (size_t)6144 * 2;
    unsigned short* cW2 = (unsigned short*)ws;  ws += (size_t)6291456 * 2;
    unsigned short* cb2 = (unsigned short*)ws;  ws += (size_t)3072 * 2;
    float* maskf = (float*)ws;                  ws += (size_t)16384 * 4;
    int* flag = (int*)ws;                       ws += 256;

    detect_dtype<<<1, 256, 0, stream>>>((const unsigned int*)x, flag);

    auto conv = [&](const void* s, unsigned short* d, int n) {
        conv_to_bf16<<<(n / 8 + 255) / 256, 256, 0, stream>>>(s, d, n, flag);
    };
    conv(d_in[2], cWq, 393216);
    conv(d_in[3], cWk, 393216);
    conv(d_in[4], cWv, 393216);
    conv(d_in[5], cWo, 393216);
    conv(d_in[6], cbo, 3072);
    conv(d_in[7], cW1, 6291456);
    conv(d_in[8], cb1, 6144);
    conv(d_in[9], cW2, 6291456);
    conv(d_in[10], cb2, 3072);

    mask_expand<<<64, 256, 0, stream>>>(mask, maskf);
    init_h<<<8192, 256, 0, stream>>>(x, hf, hb, flag);

    for (int l = 0; l < 3; ++l) {
        const unsigned short* wq  = cWq + (size_t)l * 131072;
        const unsigned short* wk  = cWk + (size_t)l * 131072;
        const unsigned short* wv  = cWv + (size_t)l * 131072;
        const unsigned short* wo  = cWo + (size_t)l * 131072;
        const unsigned short* bol = cbo + (size_t)l * 1024;
        const unsigned short* w1  = cW1 + (size_t)l * 2097152;
        const unsigned short* b1l = cb1 + (size_t)l * 2048;
        const unsigned short* w2  = cW2 + (size_t)l * 2097152;
        const unsigned short* b2l = cb2 + (size_t)l * 1024;

        gemm_bt<EPI_NONE><<<dim3(128, 1, 3), 256, 0, stream>>>(
            hb, wq, wk, wv, q, k, v, nullptr, nullptr, nullptr, 128, 1024);
        attn_mfma<<<1024, 128, 0, stream>>>(q, k, v, maskf, ao);
        gemm_bt<EPI_BIAS_RES><<<dim3(128, 8, 1), 256, 0, stream>>>(
            ao, wo, wo, wo, nullptr, nullptr, nullptr, bol, hf, hb, 1024, 128);
        // FFN1: 256^2 8-phase (measured ~79us)
        gemm256_bt<EPI_BIAS_RELU><<<dim3(64, 8, 1), 512, 0, stream>>>(
            hb, w1, act, b1l, nullptr, nullptr, 2048, 1024);
        // FFN2: 128^2, 4 blocks/CU overlaps residual epilogue (measured ~116us)
        gemm_bt<EPI_BIAS_RES><<<dim3(128, 8, 1), 256, 0, stream>>>(
            act, w2, w2, w2, nullptr, nullptr, nullptr, b2l, hf, hb, 1024, 2048);
    }

    write_h<<<16384, 256, 0, stream>>>(hf, d_out, flag);
    mean_kernel<<<128, 256, 0, stream>>>(hf, d_out, flag);
}

// Round 9
// 1229.617 us; speedup vs baseline: 1.3389x; 1.0058x over previous
//
#include <hip/hip_runtime.h>
#include <stdint.h>

// Problem: B=32, N=512, E=1024, H=8, L=3, FF=2048, KD=128, DK=16
// Transport dtype (f32 vs bf16) detected on device; compute bf16 MFMA + f32 master h.
// FFN1 (N=2048,K=1024): gemm256_bt, 512 blocks = 2 rounds (epilogue overlap).
// FFN2 (N=1024,K=2048): gemm128x256_bt, 8-phase 128x256 tile, 512 blocks = 2 rounds
// (256^2 at 256 blocks = 1 round exposed its epilogue -> 137us; gemm_bt was 116).

typedef __attribute__((ext_vector_type(8))) short short8;
typedef __attribute__((ext_vector_type(4))) float floatx4;

#define NORM_ 0.08838834764831845f   // 1/sqrt(128)

__device__ __forceinline__ float bf2f(unsigned short u) {
    union { unsigned int i; float f; } x; x.i = ((unsigned int)u) << 16; return x.f;
}
__device__ __forceinline__ unsigned short f2bf(float f) {  // RNE
    union { float f; unsigned int i; } x; x.f = f;
    unsigned int u = x.i;
    u += 0x7FFFu + ((u >> 16) & 1u);
    return (unsigned short)(u >> 16);
}
__device__ __forceinline__ void async_cp16(const void* g, void* l) {
    __builtin_amdgcn_global_load_lds((const __attribute__((address_space(1))) void*)g,
                                     (__attribute__((address_space(3))) void*)l, 16, 0, 0);
}
__device__ __forceinline__ floatx4 mfma16(short8 a, short8 b, floatx4 c) {
    return __builtin_amdgcn_mfma_f32_16x16x32_bf16(a, b, c, 0, 0, 0);
}

// ---- transport dtype detection -------------------------------------------
__global__ __launch_bounds__(256) void detect_dtype(const unsigned int* __restrict__ x,
                                                    int* __restrict__ flag)
{
    __shared__ int good, bad;
    if (threadIdx.x == 0) { good = 0; bad = 0; }
    __syncthreads();
    int g = 0, b = 0;
    for (int i = threadIdx.x; i < 4096; i += 256) {
        unsigned int lo = x[i] & 0xFFFFu;
        if (lo != 0u) {
            unsigned int e = (lo >> 7) & 0xFFu;
            if (e >= 90u && e <= 145u) ++g; else ++b;
        }
    }
    atomicAdd(&good, g); atomicAdd(&bad, b);
    __syncthreads();
    if (threadIdx.x == 0) *flag = (bad > good) ? 1 : 0;   // 1 = f32 transport
}

__global__ __launch_bounds__(256) void conv_to_bf16(const void* __restrict__ src,
                                                    unsigned short* __restrict__ dst,
                                                    int n, const int* __restrict__ flag)
{
    const int i = (blockIdx.x * 256 + threadIdx.x) * 8;
    if (i >= n) return;
    if (*flag) {
        const float* s = (const float*)src + i;
        floatx4 a = *(const floatx4*)s;
        floatx4 b = *(const floatx4*)(s + 4);
        short8 o;
        o[0] = (short)f2bf(a[0]); o[1] = (short)f2bf(a[1]);
        o[2] = (short)f2bf(a[2]); o[3] = (short)f2bf(a[3]);
        o[4] = (short)f2bf(b[0]); o[5] = (short)f2bf(b[1]);
        o[6] = (short)f2bf(b[2]); o[7] = (short)f2bf(b[3]);
        *(short8*)(dst + i) = o;
    } else {
        *(short8*)(dst + i) = *(const short8*)((const unsigned short*)src + i);
    }
}

__global__ __launch_bounds__(256) void init_h(const void* __restrict__ x,
                                              float* __restrict__ hf,
                                              unsigned short* __restrict__ hb,
                                              const int* __restrict__ flag)
{
    const size_t i = ((size_t)blockIdx.x * 256 + threadIdx.x) * 8;
    if (*flag) {
        const float* s = (const float*)x + i;
        floatx4 a = *(const floatx4*)s;
        floatx4 b = *(const floatx4*)(s + 4);
        short8 o;
        o[0] = (short)f2bf(a[0]); o[1] = (short)f2bf(a[1]);
        o[2] = (short)f2bf(a[2]); o[3] = (short)f2bf(a[3]);
        o[4] = (short)f2bf(b[0]); o[5] = (short)f2bf(b[1]);
        o[6] = (short)f2bf(b[2]); o[7] = (short)f2bf(b[3]);
        *(short8*)(hb + i) = o;
        *(floatx4*)(hf + i) = a;
        *(floatx4*)(hf + i + 4) = b;
    } else {
        short8 v = *(const short8*)((const unsigned short*)x + i);
        *(short8*)(hb + i) = v;
        #pragma unroll
        for (int e = 0; e < 8; ++e) hf[i + e] = bf2f((unsigned short)v[e]);
    }
}

__global__ __launch_bounds__(256) void mask_expand(const unsigned int* __restrict__ mraw,
                                                   float* __restrict__ maskf)
{
    __shared__ unsigned int r[4];
    if (threadIdx.x < 4) r[threadIdx.x] = 0;
    __syncthreads();
    unsigned int gt1 = 0, badb = 0, badh = 0, lo3f = 0;
    for (int i = threadIdx.x; i < 4096; i += 256) {
        unsigned int w = mraw[i];
        if (w > 1u) gt1 = 1;
        if (w & 0xFEFEFEFEu) badb = 1;
        unsigned int lo = w & 0xFFFFu, hi = w >> 16;
        if ((lo != 0u && lo != 0x3F80u) || (hi != 0u && hi != 0x3F80u)) badh = 1;
        if (lo == 0x3F80u) lo3f = 1;
    }
    if (gt1) atomicOr(&r[0], 1u);
    if (badb) atomicOr(&r[1], 1u);
    if (badh) atomicOr(&r[2], 1u);
    if (lo3f) atomicOr(&r[3], 1u);
    __syncthreads();
    int cls;
    if (!r[0]) cls = 0;
    else if (!r[1]) cls = 1;
    else if (!r[2]) cls = r[3] ? 2 : 3;
    else cls = 0;

    const int gid = blockIdx.x * 256 + threadIdx.x;
    bool m;
    if (cls == 0)      m = ((const int*)mraw)[gid] != 0;
    else if (cls == 1) m = ((const unsigned char*)mraw)[gid] != 0;
    else if (cls == 2) m = ((const unsigned short*)mraw)[gid] != 0;
    else               m = mraw[gid] != 0u;
    maskf[gid] = m ? 1.0f : 0.0f;
}

enum { EPI_NONE = 0, EPI_BIAS_RELU = 1, EPI_BIAS_RES = 2 };

// ---------------------------------------------------------------------------
// 128x128 tile kernel (proven) — QKV (N=128), Wo (K=128).
// ---------------------------------------------------------------------------
template<int EPI>
__global__ __launch_bounds__(256) void gemm_bt(
    const unsigned short* __restrict__ A,
    const unsigned short* __restrict__ Bq,
    const unsigned short* __restrict__ Bk,
    const unsigned short* __restrict__ Bv,
    unsigned short* __restrict__ Cq,
    unsigned short* __restrict__ Ck,
    unsigned short* __restrict__ Cv,
    const unsigned short* __restrict__ bias,
    float* __restrict__ hf,
    unsigned short* __restrict__ hb,
    int N, int K)
{
    constexpr int BK = 64;
    __shared__ __align__(16) unsigned short As[2][128 * BK];   // 2 x 16 KB
    __shared__ __align__(16) unsigned short Bs[2][128 * BK];   // 2 x 16 KB

    const int t = threadIdx.x;
    const int lane = t & 63;
    const int wave = t >> 6;
    const int bm = blockIdx.x;
    const int bn = blockIdx.y;
    const int bz = blockIdx.z;

    const unsigned short* Bmat = (bz == 0) ? Bq : ((bz == 1) ? Bk : Bv);
    unsigned short* C = (bz == 0) ? Cq : ((bz == 1) ? Ck : Cv);

    const int wm = (wave >> 1) * 64;
    const int wn = (wave & 1) * 64;

    const int srow = t >> 3;                               // 0..31
    const int scol = (((t & 7) ^ ((t >> 3) & 7)) * 8);     // swizzled source col
    const unsigned short* Ag = A + (size_t)(bm * 128 + srow) * K + scol;
    const unsigned short* Bg = Bmat + (size_t)(bn * 128 + srow) * K + scol;
    const size_t gstep = (size_t)32 * K;                   // 32 rows per round

    const int fl = lane & 15;
    const int g = lane >> 4;
    const int s7 = fl & 7;
    const int swz0 = (g ^ s7) * 8;          // ks = 0 chunk
    const int swz1 = ((g + 4) ^ s7) * 8;    // ks = 32 chunk
    int aoff[4], boff[4];
    #pragma unroll
    for (int i = 0; i < 4; ++i) {
        aoff[i] = (wm + i * 16 + fl) * BK;
        boff[i] = (wn + i * 16 + fl) * BK;
    }

    floatx4 acc[4][4];
    #pragma unroll
    for (int i = 0; i < 4; ++i)
        #pragma unroll
        for (int j = 0; j < 4; ++j) {
            acc[i][j][0] = 0.f; acc[i][j][1] = 0.f;
            acc[i][j][2] = 0.f; acc[i][j][3] = 0.f;
        }

    const int NT = K / BK;

    #pragma unroll
    for (int r = 0; r < 4; ++r) {
        async_cp16(Ag + r * gstep, &As[0][t * 8 + r * 2048]);
        async_cp16(Bg + r * gstep, &Bs[0][t * 8 + r * 2048]);
    }

    for (int it = 0; it < NT; ++it) {
        const int cur = it & 1;
        if (it + 1 < NT) {
            const int nxt = cur ^ 1;
            const size_t koff = (size_t)(it + 1) * BK;
            #pragma unroll
            for (int r = 0; r < 4; ++r) {
                async_cp16(Ag + koff + r * gstep, &As[nxt][t * 8 + r * 2048]);
                async_cp16(Bg + koff + r * gstep, &Bs[nxt][t * 8 + r * 2048]);
            }
            asm volatile("s_waitcnt vmcnt(8)" ::: "memory");
        } else {
            asm volatile("s_waitcnt vmcnt(0)" ::: "memory");
        }
        asm volatile("s_barrier" ::: "memory");

        #pragma unroll
        for (int ks = 0; ks < 2; ++ks) {
            const int sw = ks ? swz1 : swz0;
            short8 af[4], bfr[4];
            #pragma unroll
            for (int i = 0; i < 4; ++i) af[i] = *(const short8*)&As[cur][aoff[i] + sw];
            #pragma unroll
            for (int j = 0; j < 4; ++j) bfr[j] = *(const short8*)&Bs[cur][boff[j] + sw];
            #pragma unroll
            for (int i = 0; i < 4; ++i)
                #pragma unroll
                for (int j = 0; j < 4; ++j)
                    acc[i][j] = __builtin_amdgcn_mfma_f32_16x16x32_bf16(af[i], bfr[j], acc[i][j], 0, 0, 0);
        }
        if (it + 1 < NT)
            asm volatile("s_barrier" ::: "memory");
    }

    const int r0 = (lane >> 4) * 4;
    #pragma unroll
    for (int j = 0; j < 4; ++j) {
        const int gcol = bn * 128 + wn + j * 16 + fl;
        float bval = 0.f;
        if (EPI != EPI_NONE) bval = bf2f(bias[gcol]);
        #pragma unroll
        for (int i = 0; i < 4; ++i) {
            const int growb = bm * 128 + wm + i * 16 + r0;
            #pragma unroll
            for (int r = 0; r < 4; ++r) {
                const size_t idx = (size_t)(growb + r) * N + gcol;
                float v = acc[i][j][r];
                if (EPI == EPI_NONE) {
                    C[idx] = f2bf(v);
                } else if (EPI == EPI_BIAS_RELU) {
                    v += bval;
                    v = v > 0.f ? v : 0.f;
                    C[idx] = f2bf(v);
                } else {
                    float nh = hf[idx] + v + bval;
                    hf[idx] = nh;
                    hb[idx] = f2bf(nh);
                }
            }
        }
    }
}

// ---------------------------------------------------------------------------
// 256x256 tile, BK=64, 512 threads (8 waves, 2M x 4N), 8-phase interleaved
// schedule with counted vmcnt. FFN1 (512 blocks = 2 rounds).
// ---------------------------------------------------------------------------
template<int EPI>
__global__ __launch_bounds__(512) void gemm256_bt(
    const unsigned short* __restrict__ A,
    const unsigned short* __restrict__ Bmat,
    unsigned short* __restrict__ C,
    const unsigned short* __restrict__ bias,
    float* __restrict__ hf,
    unsigned short* __restrict__ hb,
    int N, int K)
{
    __shared__ __align__(16) unsigned short As[2][16384];   // 2 x 256 x 64 (two 128-row halves)
    __shared__ __align__(16) unsigned short Bs[2][16384];

    const int t = threadIdx.x;           // 0..511
    const int lane = t & 63;
    const int wave = t >> 6;             // 0..7
    const int bm = blockIdx.x;
    const int bn = blockIdx.y;

    const int wm = (wave >> 2) * 128;    // waves 0-3 -> rows 0..127, 4-7 -> 128..255
    const int wn = (wave & 3) * 64;

    const int srow = t >> 3;                               // 0..63
    const int scol = ((t & 7) ^ (srow & 7)) * 8;
    const unsigned short* Ag = A + (size_t)(bm * 256 + srow) * K + scol;
    const unsigned short* Bg = Bmat + (size_t)(bn * 256 + srow) * K + scol;
    const size_t rows64 = (size_t)64 * K;

    const int fl = lane & 15;
    const int g = lane >> 4;
    const int s7 = fl & 7;
    const int c0 = (g ^ s7) * 8;           // ks=0 chunk offset (ushorts)
    const int c1 = ((4 + g) ^ s7) * 8;     // ks=1
    const int abase = (wm + fl) * 64;
    const int bbase = (wn + fl) * 64;

    floatx4 acc[8][4];
    #pragma unroll
    for (int i = 0; i < 8; ++i)
        #pragma unroll
        for (int j = 0; j < 4; ++j) {
            acc[i][j][0] = 0.f; acc[i][j][1] = 0.f;
            acc[i][j][2] = 0.f; acc[i][j][3] = 0.f;
        }

    auto stgA = [&](int buf, int h, size_t koff) {
        const unsigned short* s = Ag + (size_t)(h * 128) * K + koff;
        unsigned short* d = &As[buf][h * 8192 + t * 8];
        async_cp16(s, d);
        async_cp16(s + rows64, d + 4096);
    };
    auto stgB = [&](int buf, int h, size_t koff) {
        const unsigned short* s = Bg + (size_t)(h * 128) * K + koff;
        unsigned short* d = &Bs[buf][h * 8192 + t * 8];
        async_cp16(s, d);
        async_cp16(s + rows64, d + 4096);
    };

    const int NT = K >> 6;

    // prologue: tile0 (4 half-tiles) + A halves of tile1; wait tile0 only.
    stgA(0, 0, 0); stgA(0, 1, 0); stgB(0, 0, 0); stgB(0, 1, 0);
    if (NT > 1) {
        stgA(1, 0, 64); stgA(1, 1, 64);
        asm volatile("s_waitcnt vmcnt(4)" ::: "memory");
    } else {
        asm volatile("s_waitcnt vmcnt(0)" ::: "memory");
    }
    asm volatile("s_barrier" ::: "memory");

    for (int tt = 0; tt < NT; ++tt) {
        const int R = tt & 1;
        const int S = R ^ 1;
        const size_t k1 = (size_t)(tt + 1) << 6;
        const size_t k2 = (size_t)(tt + 2) << 6;
        const bool p1 = (tt + 1 < NT);
        const bool p2 = (tt + 2 < NT);

        short8 a0[8], a1[8], b0[4], b1[4];

        // ---- phase 1 ----
        #pragma unroll
        for (int i = 0; i < 8; ++i) a0[i] = *(const short8*)&As[R][abase + i * 1024 + c0];
        #pragma unroll
        for (int j = 0; j < 4; ++j) b0[j] = *(const short8*)&Bs[R][bbase + j * 1024 + c0];
        if (p1) stgB(S, 0, k1);
        asm volatile("s_barrier" ::: "memory");
        asm volatile("s_waitcnt lgkmcnt(0)" ::: "memory");
        __builtin_amdgcn_s_setprio(1);
        #pragma unroll
        for (int i = 0; i < 8; ++i) {
            acc[i][0] = mfma16(a0[i], b0[0], acc[i][0]);
            acc[i][1] = mfma16(a0[i], b0[1], acc[i][1]);
        }
        __builtin_amdgcn_s_setprio(0);
        asm volatile("s_barrier" ::: "memory");

        // ---- phase 2 ----
        #pragma unroll
        for (int i = 0; i < 8; ++i) a1[i] = *(const short8*)&As[R][abase + i * 1024 + c1];
        #pragma unroll
        for (int j = 0; j < 4; ++j) b1[j] = *(const short8*)&Bs[R][bbase + j * 1024 + c1];
        if (p1) stgB(S, 1, k1);
        asm volatile("s_barrier" ::: "memory");
        asm volatile("s_waitcnt lgkmcnt(0)" ::: "memory");   // all buf-R reads retired
        __builtin_amdgcn_s_setprio(1);
        #pragma unroll
        for (int i = 0; i < 8; ++i) {
            acc[i][2] = mfma16(a0[i], b0[2], acc[i][2]);
            acc[i][3] = mfma16(a0[i], b0[3], acc[i][3]);
        }
        __builtin_amdgcn_s_setprio(0);
        asm volatile("s_barrier" ::: "memory");

        // ---- phase 3 (safe to restage buf R: no further LDS reads this tile) ----
        if (p2) stgA(R, 0, k2);
        asm volatile("s_barrier" ::: "memory");
        __builtin_amdgcn_s_setprio(1);
        #pragma unroll
        for (int i = 0; i < 8; ++i) {
            acc[i][0] = mfma16(a1[i], b1[0], acc[i][0]);
            acc[i][1] = mfma16(a1[i], b1[1], acc[i][1]);
        }
        __builtin_amdgcn_s_setprio(0);
        asm volatile("s_barrier" ::: "memory");

        // ---- phase 4 ----
        if (p2) stgA(R, 1, k2);
        asm volatile("s_barrier" ::: "memory");
        __builtin_amdgcn_s_setprio(1);
        #pragma unroll
        for (int i = 0; i < 8; ++i) {
            acc[i][2] = mfma16(a1[i], b1[2], acc[i][2]);
            acc[i][3] = mfma16(a1[i], b1[3], acc[i][3]);
        }
        __builtin_amdgcn_s_setprio(0);
        if (p2) asm volatile("s_waitcnt vmcnt(4)" ::: "memory");
        else    asm volatile("s_waitcnt vmcnt(0)" ::: "memory");
        asm volatile("s_barrier" ::: "memory");
    }

    const int r0 = g * 4;
    #pragma unroll
    for (int j = 0; j < 4; ++j) {
        const int gcol = bn * 256 + wn + j * 16 + fl;
        float bval = 0.f;
        if (EPI != EPI_NONE) bval = bf2f(bias[gcol]);
        #pragma unroll
        for (int i = 0; i < 8; ++i) {
            const int growb = bm * 256 + wm + i * 16 + r0;
            #pragma unroll
            for (int r = 0; r < 4; ++r) {
                const size_t idx = (size_t)(growb + r) * N + gcol;
                float v = acc[i][j][r];
                if (EPI == EPI_NONE) {
                    C[idx] = f2bf(v);
                } else if (EPI == EPI_BIAS_RELU) {
                    v += bval;
                    v = v > 0.f ? v : 0.f;
                    C[idx] = f2bf(v);
                } else {
                    float nh = hf[idx] + v + bval;
                    hf[idx] = nh;
                    hb[idx] = f2bf(nh);
                }
            }
        }
    }
}

// ---------------------------------------------------------------------------
// 128x256 tile, BK=64, 512 threads (8 waves, 2M x 4N of 64x64), same 8-phase
// counted-vmcnt schedule as gemm256_bt. LDS 96KB -> 1 block/CU; FFN2 grid
// (128,4) = 512 blocks = 2 rounds -> epilogue overlaps next round's mainloop.
// Per-tile loads: B-h0(2) ph1, B-h1(2) ph2, A(2) ph3 -> steady vmcnt(2) keeps
// only A(tt+2); drains A(tt+1)+B(tt+1) before the next tile reads them.
// Accumulation order (ks0 then ks1 per tile, ascending) == gemm_bt bit-exact.
// ---------------------------------------------------------------------------
template<int EPI>
__global__ __launch_bounds__(512) void gemm128x256_bt(
    const unsigned short* __restrict__ A,
    const unsigned short* __restrict__ Bmat,
    unsigned short* __restrict__ C,
    const unsigned short* __restrict__ bias,
    float* __restrict__ hf,
    unsigned short* __restrict__ hb,
    int N, int K)
{
    __shared__ __align__(16) unsigned short As[2][8192];    // 2 x 128 x 64 = 32 KB
    __shared__ __align__(16) unsigned short Bs[2][16384];   // 2 x 256 x 64 = 64 KB

    const int t = threadIdx.x;           // 0..511
    const int lane = t & 63;
    const int wave = t >> 6;             // 0..7
    const int bm = blockIdx.x;
    const int bn = blockIdx.y;

    const int wm = (wave >> 2) * 64;     // 2 M-groups of 64 rows
    const int wn = (wave & 3) * 64;      // 4 N-groups of 64 cols

    const int srow = t >> 3;                               // 0..63
    const int scol = ((t & 7) ^ (srow & 7)) * 8;
    const unsigned short* Ag = A + (size_t)(bm * 128 + srow) * K + scol;
    const unsigned short* Bg = Bmat + (size_t)(bn * 256 + srow) * K + scol;
    const size_t rows64 = (size_t)64 * K;

    const int fl = lane & 15;
    const int g = lane >> 4;
    const int s7 = fl & 7;
    const int c0 = (g ^ s7) * 8;           // ks=0 chunk offset (ushorts)
    const int c1 = ((4 + g) ^ s7) * 8;     // ks=1
    const int abase = (wm + fl) * 64;
    const int bbase = (wn + fl) * 64;

    floatx4 acc[4][4];
    #pragma unroll
    for (int i = 0; i < 4; ++i)
        #pragma unroll
        for (int j = 0; j < 4; ++j) {
            acc[i][j][0] = 0.f; acc[i][j][1] = 0.f;
            acc[i][j][2] = 0.f; acc[i][j][3] = 0.f;
        }

    auto stgA = [&](int buf, size_t koff) {      // 128 rows, 2 cp16/thread
        const unsigned short* s = Ag + koff;
        unsigned short* d = &As[buf][t * 8];
        async_cp16(s, d);
        async_cp16(s + rows64, d + 4096);
    };
    auto stgB = [&](int buf, int h, size_t koff) {  // half-tile (128 rows)
        const unsigned short* s = Bg + (size_t)(h * 128) * K + koff;
        unsigned short* d = &Bs[buf][h * 8192 + t * 8];
        async_cp16(s, d);
        async_cp16(s + rows64, d + 4096);
    };

    const int NT = K >> 6;

    // prologue: A(0)(2) + B(0)(4) + A(1)(2); vmcnt(2) keeps A(1) in flight.
    stgA(0, 0); stgB(0, 0, 0); stgB(0, 1, 0);
    if (NT > 1) {
        stgA(1, 64);
        asm volatile("s_waitcnt vmcnt(2)" ::: "memory");
    } else {
        asm volatile("s_waitcnt vmcnt(0)" ::: "memory");
    }
    asm volatile("s_barrier" ::: "memory");

    for (int tt = 0; tt < NT; ++tt) {
        const int R = tt & 1;
        const int S = R ^ 1;
        const size_t k1 = (size_t)(tt + 1) << 6;
        const size_t k2 = (size_t)(tt + 2) << 6;
        const bool p1 = (tt + 1 < NT);
        const bool p2 = (tt + 2 < NT);

        short8 a0[4], a1[4], b0[4], b1[4];

        // ---- phase 1 ----
        #pragma unroll
        for (int i = 0; i < 4; ++i) a0[i] = *(const short8*)&As[R][abase + i * 1024 + c0];
        #pragma unroll
        for (int j = 0; j < 4; ++j) b0[j] = *(const short8*)&Bs[R][bbase + j * 1024 + c0];
        if (p1) stgB(S, 0, k1);
        asm volatile("s_barrier" ::: "memory");
        asm volatile("s_waitcnt lgkmcnt(0)" ::: "memory");
        __builtin_amdgcn_s_setprio(1);
        #pragma unroll
        for (int i = 0; i < 4; ++i) {
            acc[i][0] = mfma16(a0[i], b0[0], acc[i][0]);
            acc[i][1] = mfma16(a0[i], b0[1], acc[i][1]);
        }
        __builtin_amdgcn_s_setprio(0);
        asm volatile("s_barrier" ::: "memory");

        // ---- phase 2 ----
        #pragma unroll
        for (int i = 0; i < 4; ++i) a1[i] = *(const short8*)&As[R][abase + i * 1024 + c1];
        #pragma unroll
        for (int j = 0; j < 4; ++j) b1[j] = *(const short8*)&Bs[R][bbase + j * 1024 + c1];
        if (p1) stgB(S, 1, k1);
        asm volatile("s_barrier" ::: "memory");
        asm volatile("s_waitcnt lgkmcnt(0)" ::: "memory");   // all buf-R reads retired
        __builtin_amdgcn_s_setprio(1);
        #pragma unroll
        for (int i = 0; i < 4; ++i) {
            acc[i][2] = mfma16(a0[i], b0[2], acc[i][2]);
            acc[i][3] = mfma16(a0[i], b0[3], acc[i][3]);
        }
        __builtin_amdgcn_s_setprio(0);
        asm volatile("s_barrier" ::: "memory");

        // ---- phase 3 (safe to restage As[R]: reads retired at ph2 lgkmcnt) ----
        if (p2) stgA(R, k2);
        asm volatile("s_barrier" ::: "memory");
        __builtin_amdgcn_s_setprio(1);
        #pragma unroll
        for (int i = 0; i < 4; ++i) {
            acc[i][0] = mfma16(a1[i], b1[0], acc[i][0]);
            acc[i][1] = mfma16(a1[i], b1[1], acc[i][1]);
        }
        __builtin_amdgcn_s_setprio(0);
        asm volatile("s_barrier" ::: "memory");

        // ---- phase 4 ----
        __builtin_amdgcn_s_setprio(1);
        #pragma unroll
        for (int i = 0; i < 4; ++i) {
            acc[i][2] = mfma16(a1[i], b1[2], acc[i][2]);
            acc[i][3] = mfma16(a1[i], b1[3], acc[i][3]);
        }
        __builtin_amdgcn_s_setprio(0);
        if (p2) asm volatile("s_waitcnt vmcnt(2)" ::: "memory");
        else    asm volatile("s_waitcnt vmcnt(0)" ::: "memory");
        asm volatile("s_barrier" ::: "memory");
    }

    const int r0 = g * 4;
    #pragma unroll
    for (int j = 0; j < 4; ++j) {
        const int gcol = bn * 256 + wn + j * 16 + fl;
        float bval = 0.f;
        if (EPI != EPI_NONE) bval = bf2f(bias[gcol]);
        #pragma unroll
        for (int i = 0; i < 4; ++i) {
            const int growb = bm * 128 + wm + i * 16 + r0;
            #pragma unroll
            for (int r = 0; r < 4; ++r) {
                const size_t idx = (size_t)(growb + r) * N + gcol;
                float v = acc[i][j][r];
                if (EPI == EPI_NONE) {
                    C[idx] = f2bf(v);
                } else if (EPI == EPI_BIAS_RELU) {
                    v += bval;
                    v = v > 0.f ? v : 0.f;
                    C[idx] = f2bf(v);
                } else {
                    float nh = hf[idx] + v + bval;
                    hf[idx] = nh;
                    hb[idx] = f2bf(nh);
                }
            }
        }
    }
}

// MFMA flash attention (validated round 4). blockIdx = pair*4 + qquarter.
__global__ __launch_bounds__(128) void attn_mfma(
    const unsigned short* __restrict__ Q,
    const unsigned short* __restrict__ Kx,
    const unsigned short* __restrict__ Vx,
    const float* __restrict__ maskf,
    unsigned short* __restrict__ Out)
{
    __shared__ __align__(16) unsigned short Vt[16 * 520];
    __shared__ __align__(16) unsigned short Pb[2][64 * 40];
    __shared__ float Ms[512];
    __shared__ float cnt_s;

    const int t = threadIdx.x;
    const int lane = t & 63;
    const int wave = t >> 6;
    const int p = blockIdx.x >> 2;
    const int qq = blockIdx.x & 3;
    const int b2 = p & 31;
    const int h2 = p >> 5;
    const int fm = lane & 15;
    const int g = lane >> 4;

    const unsigned short* Qg = Q + (size_t)p * 8192;
    const unsigned short* Kg = Kx + (size_t)p * 8192;
    const unsigned short* Vg = Vx + (size_t)p * 8192;

    #pragma unroll
    for (int rr = 0; rr < 4; ++rr) {
        const int row = t * 4 + rr;
        short8 v0 = *(const short8*)&Vg[row * 16];
        short8 v1 = *(const short8*)&Vg[row * 16 + 8];
        #pragma unroll
        for (int d = 0; d < 8; ++d) Vt[d * 520 + row] = (unsigned short)v0[d];
        #pragma unroll
        for (int d = 0; d < 8; ++d) Vt[(d + 8) * 520 + row] = (unsigned short)v1[d];
    }
    if (t == 0) cnt_s = 0.f;
    __syncthreads();
    float pc = 0.f;
    #pragma unroll
    for (int it = 0; it < 4; ++it) {
        int i = it * 128 + t;
        float mv = maskf[b2 * 512 + i];
        Ms[i] = mv; pc += mv;
    }
    atomicAdd(&cnt_s, pc);
    __syncthreads();
    const float cnt = cnt_s;

    const int qbase = qq * 128 + wave * 64;
    short8 qf[4];
    #pragma unroll
    for (int i = 0; i < 4; ++i) {
        short8 z = {0,0,0,0,0,0,0,0};
        if (g < 2) z = *(const short8*)&Qg[(qbase + i * 16 + fm) * 16 + g * 8];
        qf[i] = z;
    }

    float m_[4][4], l_[4][4];
    floatx4 O[4];
    #pragma unroll
    for (int i = 0; i < 4; ++i) {
        #pragma unroll
        for (int r = 0; r < 4; ++r) { m_[i][r] = -1e30f; l_[i][r] = 0.f; }
        O[i][0] = 0.f; O[i][1] = 0.f; O[i][2] = 0.f; O[i][3] = 0.f;
    }

    unsigned short* Pw = &Pb[wave][0];

    for (int kb = 0; kb < 512; kb += 32) {
        short8 kf0 = {0,0,0,0,0,0,0,0}, kf1 = {0,0,0,0,0,0,0,0};
        if (g < 2) {
            kf0 = *(const short8*)&Kg[(kb + fm) * 16 + g * 8];
            kf1 = *(const short8*)&Kg[(kb + 16 + fm) * 16 + g * 8];
        }
        const float msk0 = Ms[kb + fm];
        const float msk1 = Ms[kb + 16 + fm];

        floatx4 zero4 = {0.f, 0.f, 0.f, 0.f};
        floatx4 s0[4], s1[4];
        #pragma unroll
        for (int i = 0; i < 4; ++i) {
            s0[i] = __builtin_amdgcn_mfma_f32_16x16x32_bf16(qf[i], kf0, zero4, 0, 0, 0);
            s1[i] = __builtin_amdgcn_mfma_f32_16x16x32_bf16(qf[i], kf1, zero4, 0, 0, 0);
        }

        #pragma unroll
        for (int i = 0; i < 4; ++i) {
            #pragma unroll
            for (int r = 0; r < 4; ++r) {
                float a0 = (msk0 != 0.f) ? -1e30f : s0[i][r] * NORM_;
                float a1 = (msk1 != 0.f) ? -1e30f : s1[i][r] * NORM_;
                float mx = fmaxf(a0, a1);
                mx = fmaxf(mx, __shfl_xor(mx, 1));
                mx = fmaxf(mx, __shfl_xor(mx, 2));
                mx = fmaxf(mx, __shfl_xor(mx, 4));
                mx = fmaxf(mx, __shfl_xor(mx, 8));
                const float mo = m_[i][r];
                const float mn = fmaxf(mo, mx);
                const float alpha = __expf(mo - mn);
                float w0 = (msk0 != 0.f) ? 0.f : __expf(a0 - mn);
                float w1 = (msk1 != 0.f) ? 0.f : __expf(a1 - mn);
                float rs = w0 + w1;
                rs += __shfl_xor(rs, 1);
                rs += __shfl_xor(rs, 2);
                rs += __shfl_xor(rs, 4);
                rs += __shfl_xor(rs, 8);
                l_[i][r] = l_[i][r] * alpha + rs;
                m_[i][r] = mn;
                O[i][r] *= alpha;
                const int qloc = i * 16 + g * 4 + r;
                Pw[qloc * 40 + fm] = f2bf(w0);
                Pw[qloc * 40 + 16 + fm] = f2bf(w1);
            }
        }
        asm volatile("s_waitcnt lgkmcnt(0)" ::: "memory");

        short8 vtf = *(const short8*)&Vt[fm * 520 + kb + g * 8];
        #pragma unroll
        for (int i = 0; i < 4; ++i) {
            short8 pf = *(const short8*)&Pw[(i * 16 + fm) * 40 + g * 8];
            O[i] = __builtin_amdgcn_mfma_f32_16x16x32_bf16(pf, vtf, O[i], 0, 0, 0);
        }
    }

    #pragma unroll
    for (int i = 0; i < 4; ++i) {
        #pragma unroll
        for (int r = 0; r < 4; ++r) {
            const float M = fmaxf(m_[i][r], -30.f);
            const float adj = __expf(m_[i][r] - M);
            const float lf = l_[i][r] * adj + cnt * __expf(-30.f - M);
            const float oval = O[i][r] * adj / lf;
            const int n = qbase + i * 16 + g * 4 + r;
            Out[((size_t)(b2 * 512 + n)) * 128 + h2 * 16 + fm] = f2bf(oval);
        }
    }
}

__global__ __launch_bounds__(256) void write_h(const float* __restrict__ hf,
                                               void* __restrict__ out,
                                               const int* __restrict__ flag)
{
    const size_t i = ((size_t)blockIdx.x * 256 + threadIdx.x) * 4;
    floatx4 v = *(const floatx4*)&hf[i];
    if (*flag) {
        *(floatx4*)((float*)out + i) = v;
    } else {
        unsigned int p0 = (unsigned int)f2bf(v[0]) | ((unsigned int)f2bf(v[1]) << 16);
        unsigned int p1 = (unsigned int)f2bf(v[2]) | ((unsigned int)f2bf(v[3]) << 16);
        unsigned int* o = (unsigned int*)((unsigned short*)out + i);
        o[0] = p0; o[1] = p1;
    }
}

__global__ __launch_bounds__(256) void mean_kernel(const float* __restrict__ hf,
                                                   void* __restrict__ out,
                                                   const int* __restrict__ flag)
{
    const int b = blockIdx.x >> 2;
    const int e = ((blockIdx.x & 3) * 256) + threadIdx.x;
    float s = 0.f;
    for (int n = 0; n < 512; ++n) s += hf[((size_t)(b * 512 + n)) * 1024 + e];
    s *= (1.0f / 512.0f);
    const size_t off = (size_t)16384 * 1024 + b * 1024 + e;
    if (*flag) ((float*)out)[off] = s;
    else       ((unsigned short*)out)[off] = f2bf(s);
}

extern "C" void kernel_launch(void* const* d_in, const int* in_sizes, int n_in,
                              void* d_out, int out_size, void* d_ws, size_t ws_size,
                              hipStream_t stream)
{
    const void* x  = d_in[0];
    const unsigned int* mask = (const unsigned int*)d_in[1];

    char* ws = (char*)d_ws;
    float* hf = (float*)ws;                     ws += (size_t)16384 * 1024 * 4;   // 64 MB
    unsigned short* hb = (unsigned short*)ws;   ws += (size_t)16384 * 1024 * 2;   // 32 MB
    char* shared_rg = ws;                       ws += (size_t)16384 * 2048 * 2;   // 64 MB
    unsigned short* act = (unsigned short*)shared_rg;
    unsigned short* q  = (unsigned short*)shared_rg;
    unsigned short* k  = q + (size_t)16384 * 128;
    unsigned short* v  = k + (size_t)16384 * 128;
    unsigned short* ao = v + (size_t)16384 * 128;
    unsigned short* cWq = (unsigned short*)ws;  ws += (size_t)393216 * 2;
    unsigned short* cWk = (unsigned short*)ws;  ws += (size_t)393216 * 2;
    unsigned short* cWv = (unsigned short*)ws;  ws += (size_t)393216 * 2;
    unsigned short* cWo = (unsigned short*)ws;  ws += (size_t)393216 * 2;
    unsigned short* cbo = (unsigned short*)ws;  ws += (size_t)3072 * 2;
    unsigned short* cW1 = (unsigned short*)ws;  ws += (size_t)6291456 * 2;
    unsigned short* cb1 = (unsigned short*)ws;  ws += (size_t)6144 * 2;
    unsigned short* cW2 = (unsigned short*)ws;  ws += (size_t)6291456 * 2;
    unsigned short* cb2 = (unsigned short*)ws;  ws += (size_t)3072 * 2;
    float* maskf = (float*)ws;                  ws += (size_t)16384 * 4;
    int* flag = (int*)ws;                       ws += 256;

    detect_dtype<<<1, 256, 0, stream>>>((const unsigned int*)x, flag);

    auto conv = [&](const void* s, unsigned short* d, int n) {
        conv_to_bf16<<<(n / 8 + 255) / 256, 256, 0, stream>>>(s, d, n, flag);
    };
    conv(d_in[2], cWq, 393216);
    conv(d_in[3], cWk, 393216);
    conv(d_in[4], cWv, 393216);
    conv(d_in[5], cWo, 393216);
    conv(d_in[6], cbo, 3072);
    conv(d_in[7], cW1, 6291456);
    conv(d_in[8], cb1, 6144);
    conv(d_in[9], cW2, 6291456);
    conv(d_in[10], cb2, 3072);

    mask_expand<<<64, 256, 0, stream>>>(mask, maskf);
    init_h<<<8192, 256, 0, stream>>>(x, hf, hb, flag);

    for (int l = 0; l < 3; ++l) {
        const unsigned short* wq  = cWq + (size_t)l * 131072;
        const unsigned short* wk  = cWk + (size_t)l * 131072;
        const unsigned short* wv  = cWv + (size_t)l * 131072;
        const unsigned short* wo  = cWo + (size_t)l * 131072;
        const unsigned short* bol = cbo + (size_t)l * 1024;
        const unsigned short* w1  = cW1 + (size_t)l * 2097152;
        const unsigned short* b1l = cb1 + (size_t)l * 2048;
        const unsigned short* w2  = cW2 + (size_t)l * 2097152;
        const unsigned short* b2l = cb2 + (size_t)l * 1024;

        gemm_bt<EPI_NONE><<<dim3(128, 1, 3), 256, 0, stream>>>(
            hb, wq, wk, wv, q, k, v, nullptr, nullptr, nullptr, 128, 1024);
        attn_mfma<<<1024, 128, 0, stream>>>(q, k, v, maskf, ao);
        gemm_bt<EPI_BIAS_RES><<<dim3(128, 8, 1), 256, 0, stream>>>(
            ao, wo, wo, wo, nullptr, nullptr, nullptr, bol, hf, hb, 1024, 128);
        // FFN1: 256^2 8-phase, 512 blocks = 2 rounds
        gemm256_bt<EPI_BIAS_RELU><<<dim3(64, 8, 1), 512, 0, stream>>>(
            hb, w1, act, b1l, nullptr, nullptr, 2048, 1024);
        // FFN2: 128x256 8-phase, 512 blocks = 2 rounds (epilogue overlap)
        gemm128x256_bt<EPI_BIAS_RES><<<dim3(128, 4, 1), 512, 0, stream>>>(
            act, w2, nullptr, b2l, hf, hb, 1024, 2048);
    }

    write_h<<<16384, 256, 0, stream>>>(hf, d_out, flag);
    mean_kernel<<<128, 256, 0, stream>>>(hf, d_out, flag);
}

// Round 15
// 1166.152 us; speedup vs baseline: 1.4118x; 1.0544x over previous
//
#include <hip/hip_runtime.h>
#include <stdint.h>

// Problem: B=32, N=512, E=1024, H=8, L=3, FF=2048, KD=128, DK=16
// FFN epilogues now LDS-bounced for fully-coalesced global stores (r9 counters:
// WRITE_SIZE 1.6x ideal from 32B bf16 / 64B f32 scattered segments).

typedef __attribute__((ext_vector_type(8))) short short8;
typedef __attribute__((ext_vector_type(4))) short shortx4;
typedef __attribute__((ext_vector_type(4))) float floatx4;

#define NORM_ 0.08838834764831845f   // 1/sqrt(128)

__device__ __forceinline__ float bf2f(unsigned short u) {
    union { unsigned int i; float f; } x; x.i = ((unsigned int)u) << 16; return x.f;
}
__device__ __forceinline__ unsigned short f2bf(float f) {  // RNE
    union { float f; unsigned int i; } x; x.f = f;
    unsigned int u = x.i;
    u += 0x7FFFu + ((u >> 16) & 1u);
    return (unsigned short)(u >> 16);
}
__device__ __forceinline__ void async_cp16(const void* g, void* l) {
    __builtin_amdgcn_global_load_lds((const __attribute__((address_space(1))) void*)g,
                                     (__attribute__((address_space(3))) void*)l, 16, 0, 0);
}
__device__ __forceinline__ floatx4 mfma16(short8 a, short8 b, floatx4 c) {
    return __builtin_amdgcn_mfma_f32_16x16x32_bf16(a, b, c, 0, 0, 0);
}

// ---- transport dtype detection -------------------------------------------
__global__ __launch_bounds__(256) void detect_dtype(const unsigned int* __restrict__ x,
                                                    int* __restrict__ flag)
{
    __shared__ int good, bad;
    if (threadIdx.x == 0) { good = 0; bad = 0; }
    __syncthreads();
    int g = 0, b = 0;
    for (int i = threadIdx.x; i < 4096; i += 256) {
        unsigned int lo = x[i] & 0xFFFFu;
        if (lo != 0u) {
            unsigned int e = (lo >> 7) & 0xFFu;
            if (e >= 90u && e <= 145u) ++g; else ++b;
        }
    }
    atomicAdd(&good, g); atomicAdd(&bad, b);
    __syncthreads();
    if (threadIdx.x == 0) *flag = (bad > good) ? 1 : 0;   // 1 = f32 transport
}

__global__ __launch_bounds__(256) void conv_to_bf16(const void* __restrict__ src,
                                                    unsigned short* __restrict__ dst,
                                                    int n, const int* __restrict__ flag)
{
    const int i = (blockIdx.x * 256 + threadIdx.x) * 8;
    if (i >= n) return;
    if (*flag) {
        const float* s = (const float*)src + i;
        floatx4 a = *(const floatx4*)s;
        floatx4 b = *(const floatx4*)(s + 4);
        short8 o;
        o[0] = (short)f2bf(a[0]); o[1] = (short)f2bf(a[1]);
        o[2] = (short)f2bf(a[2]); o[3] = (short)f2bf(a[3]);
        o[4] = (short)f2bf(b[0]); o[5] = (short)f2bf(b[1]);
        o[6] = (short)f2bf(b[2]); o[7] = (short)f2bf(b[3]);
        *(short8*)(dst + i) = o;
    } else {
        *(short8*)(dst + i) = *(const short8*)((const unsigned short*)src + i);
    }
}

__global__ __launch_bounds__(256) void init_h(const void* __restrict__ x,
                                              float* __restrict__ hf,
                                              unsigned short* __restrict__ hb,
                                              const int* __restrict__ flag)
{
    const size_t i = ((size_t)blockIdx.x * 256 + threadIdx.x) * 8;
    if (*flag) {
        const float* s = (const float*)x + i;
        floatx4 a = *(const floatx4*)s;
        floatx4 b = *(const floatx4*)(s + 4);
        short8 o;
        o[0] = (short)f2bf(a[0]); o[1] = (short)f2bf(a[1]);
        o[2] = (short)f2bf(a[2]); o[3] = (short)f2bf(a[3]);
        o[4] = (short)f2bf(b[0]); o[5] = (short)f2bf(b[1]);
        o[6] = (short)f2bf(b[2]); o[7] = (short)f2bf(b[3]);
        *(short8*)(hb + i) = o;
        *(floatx4*)(hf + i) = a;
        *(floatx4*)(hf + i + 4) = b;
    } else {
        short8 v = *(const short8*)((const unsigned short*)x + i);
        *(short8*)(hb + i) = v;
        #pragma unroll
        for (int e = 0; e < 8; ++e) hf[i + e] = bf2f((unsigned short)v[e]);
    }
}

__global__ __launch_bounds__(256) void mask_expand(const unsigned int* __restrict__ mraw,
                                                   float* __restrict__ maskf)
{
    __shared__ unsigned int r[4];
    if (threadIdx.x < 4) r[threadIdx.x] = 0;
    __syncthreads();
    unsigned int gt1 = 0, badb = 0, badh = 0, lo3f = 0;
    for (int i = threadIdx.x; i < 4096; i += 256) {
        unsigned int w = mraw[i];
        if (w > 1u) gt1 = 1;
        if (w & 0xFEFEFEFEu) badb = 1;
        unsigned int lo = w & 0xFFFFu, hi = w >> 16;
        if ((lo != 0u && lo != 0x3F80u) || (hi != 0u && hi != 0x3F80u)) badh = 1;
        if (lo == 0x3F80u) lo3f = 1;
    }
    if (gt1) atomicOr(&r[0], 1u);
    if (badb) atomicOr(&r[1], 1u);
    if (badh) atomicOr(&r[2], 1u);
    if (lo3f) atomicOr(&r[3], 1u);
    __syncthreads();
    int cls;
    if (!r[0]) cls = 0;
    else if (!r[1]) cls = 1;
    else if (!r[2]) cls = r[3] ? 2 : 3;
    else cls = 0;

    const int gid = blockIdx.x * 256 + threadIdx.x;
    bool m;
    if (cls == 0)      m = ((const int*)mraw)[gid] != 0;
    else if (cls == 1) m = ((const unsigned char*)mraw)[gid] != 0;
    else if (cls == 2) m = ((const unsigned short*)mraw)[gid] != 0;
    else               m = mraw[gid] != 0u;
    maskf[gid] = m ? 1.0f : 0.0f;
}

enum { EPI_NONE = 0, EPI_BIAS_RELU = 1, EPI_BIAS_RES = 2 };

// ---------------------------------------------------------------------------
// 128x128 tile kernel (proven) — QKV (N=128), Wo (K=128). UNCHANGED (control).
// ---------------------------------------------------------------------------
template<int EPI>
__global__ __launch_bounds__(256) void gemm_bt(
    const unsigned short* __restrict__ A,
    const unsigned short* __restrict__ Bq,
    const unsigned short* __restrict__ Bk,
    const unsigned short* __restrict__ Bv,
    unsigned short* __restrict__ Cq,
    unsigned short* __restrict__ Ck,
    unsigned short* __restrict__ Cv,
    const unsigned short* __restrict__ bias,
    float* __restrict__ hf,
    unsigned short* __restrict__ hb,
    int N, int K)
{
    constexpr int BK = 64;
    __shared__ __align__(16) unsigned short As[2][128 * BK];   // 2 x 16 KB
    __shared__ __align__(16) unsigned short Bs[2][128 * BK];   // 2 x 16 KB

    const int t = threadIdx.x;
    const int lane = t & 63;
    const int wave = t >> 6;
    const int bm = blockIdx.x;
    const int bn = blockIdx.y;
    const int bz = blockIdx.z;

    const unsigned short* Bmat = (bz == 0) ? Bq : ((bz == 1) ? Bk : Bv);
    unsigned short* C = (bz == 0) ? Cq : ((bz == 1) ? Ck : Cv);

    const int wm = (wave >> 1) * 64;
    const int wn = (wave & 1) * 64;

    const int srow = t >> 3;                               // 0..31
    const int scol = (((t & 7) ^ ((t >> 3) & 7)) * 8);     // swizzled source col
    const unsigned short* Ag = A + (size_t)(bm * 128 + srow) * K + scol;
    const unsigned short* Bg = Bmat + (size_t)(bn * 128 + srow) * K + scol;
    const size_t gstep = (size_t)32 * K;                   // 32 rows per round

    const int fl = lane & 15;
    const int g = lane >> 4;
    const int s7 = fl & 7;
    const int swz0 = (g ^ s7) * 8;          // ks = 0 chunk
    const int swz1 = ((g + 4) ^ s7) * 8;    // ks = 32 chunk
    int aoff[4], boff[4];
    #pragma unroll
    for (int i = 0; i < 4; ++i) {
        aoff[i] = (wm + i * 16 + fl) * BK;
        boff[i] = (wn + i * 16 + fl) * BK;
    }

    floatx4 acc[4][4];
    #pragma unroll
    for (int i = 0; i < 4; ++i)
        #pragma unroll
        for (int j = 0; j < 4; ++j) {
            acc[i][j][0] = 0.f; acc[i][j][1] = 0.f;
            acc[i][j][2] = 0.f; acc[i][j][3] = 0.f;
        }

    const int NT = K / BK;

    #pragma unroll
    for (int r = 0; r < 4; ++r) {
        async_cp16(Ag + r * gstep, &As[0][t * 8 + r * 2048]);
        async_cp16(Bg + r * gstep, &Bs[0][t * 8 + r * 2048]);
    }

    for (int it = 0; it < NT; ++it) {
        const int cur = it & 1;
        if (it + 1 < NT) {
            const int nxt = cur ^ 1;
            const size_t koff = (size_t)(it + 1) * BK;
            #pragma unroll
            for (int r = 0; r < 4; ++r) {
                async_cp16(Ag + koff + r * gstep, &As[nxt][t * 8 + r * 2048]);
                async_cp16(Bg + koff + r * gstep, &Bs[nxt][t * 8 + r * 2048]);
            }
            asm volatile("s_waitcnt vmcnt(8)" ::: "memory");
        } else {
            asm volatile("s_waitcnt vmcnt(0)" ::: "memory");
        }
        asm volatile("s_barrier" ::: "memory");

        #pragma unroll
        for (int ks = 0; ks < 2; ++ks) {
            const int sw = ks ? swz1 : swz0;
            short8 af[4], bfr[4];
            #pragma unroll
            for (int i = 0; i < 4; ++i) af[i] = *(const short8*)&As[cur][aoff[i] + sw];
            #pragma unroll
            for (int j = 0; j < 4; ++j) bfr[j] = *(const short8*)&Bs[cur][boff[j] + sw];
            #pragma unroll
            for (int i = 0; i < 4; ++i)
                #pragma unroll
                for (int j = 0; j < 4; ++j)
                    acc[i][j] = __builtin_amdgcn_mfma_f32_16x16x32_bf16(af[i], bfr[j], acc[i][j], 0, 0, 0);
        }
        if (it + 1 < NT)
            asm volatile("s_barrier" ::: "memory");
    }

    const int r0 = (lane >> 4) * 4;
    #pragma unroll
    for (int j = 0; j < 4; ++j) {
        const int gcol = bn * 128 + wn + j * 16 + fl;
        float bval = 0.f;
        if (EPI != EPI_NONE) bval = bf2f(bias[gcol]);
        #pragma unroll
        for (int i = 0; i < 4; ++i) {
            const int growb = bm * 128 + wm + i * 16 + r0;
            #pragma unroll
            for (int r = 0; r < 4; ++r) {
                const size_t idx = (size_t)(growb + r) * N + gcol;
                float v = acc[i][j][r];
                if (EPI == EPI_NONE) {
                    C[idx] = f2bf(v);
                } else if (EPI == EPI_BIAS_RELU) {
                    v += bval;
                    v = v > 0.f ? v : 0.f;
                    C[idx] = f2bf(v);
                } else {
                    float nh = hf[idx] + v + bval;
                    hf[idx] = nh;
                    hb[idx] = f2bf(nh);
                }
            }
        }
    }
}

// ---------------------------------------------------------------------------
// 256x256 tile, BK=64, 8-phase counted-vmcnt. FFN1 (512 blocks = 2 rounds).
// NEW: coalesced epilogue — bf16 C tile staged in LDS (XOR-swizzled), then
// written as 512B full-row segments (was 32B scattered -> WRITE amplification).
// ---------------------------------------------------------------------------
template<int EPI>
__global__ __launch_bounds__(512) void gemm256_bt(
    const unsigned short* __restrict__ A,
    const unsigned short* __restrict__ Bmat,
    unsigned short* __restrict__ C,
    const unsigned short* __restrict__ bias,
    float* __restrict__ hf,
    unsigned short* __restrict__ hb,
    int N, int K)
{
    __shared__ __align__(16) unsigned char smem[131072];
    unsigned short* AsB = (unsigned short*)smem;            // [2][16384]
    unsigned short* BsB = (unsigned short*)(smem + 65536);  // [2][16384]

    const int t = threadIdx.x;           // 0..511
    const int lane = t & 63;
    const int wave = t >> 6;             // 0..7
    const int bm = blockIdx.x;
    const int bn = blockIdx.y;

    const int wm = (wave >> 2) * 128;
    const int wn = (wave & 3) * 64;

    const int srow = t >> 3;                               // 0..63
    const int scol = ((t & 7) ^ (srow & 7)) * 8;
    const unsigned short* Ag = A + (size_t)(bm * 256 + srow) * K + scol;
    const unsigned short* Bg = Bmat + (size_t)(bn * 256 + srow) * K + scol;
    const size_t rows64 = (size_t)64 * K;

    const int fl = lane & 15;
    const int g = lane >> 4;
    const int s7 = fl & 7;
    const int c0 = (g ^ s7) * 8;
    const int c1 = ((4 + g) ^ s7) * 8;
    const int abase = (wm + fl) * 64;
    const int bbase = (wn + fl) * 64;

    floatx4 acc[8][4];
    #pragma unroll
    for (int i = 0; i < 8; ++i)
        #pragma unroll
        for (int j = 0; j < 4; ++j) {
            acc[i][j][0] = 0.f; acc[i][j][1] = 0.f;
            acc[i][j][2] = 0.f; acc[i][j][3] = 0.f;
        }

    auto stgA = [&](int buf, int h, size_t koff) {
        const unsigned short* s = Ag + (size_t)(h * 128) * K + koff;
        unsigned short* d = &AsB[buf * 16384 + h * 8192 + t * 8];
        async_cp16(s, d);
        async_cp16(s + rows64, d + 4096);
    };
    auto stgB = [&](int buf, int h, size_t koff) {
        const unsigned short* s = Bg + (size_t)(h * 128) * K + koff;
        unsigned short* d = &BsB[buf * 16384 + h * 8192 + t * 8];
        async_cp16(s, d);
        async_cp16(s + rows64, d + 4096);
    };

    const int NT = K >> 6;

    stgA(0, 0, 0); stgA(0, 1, 0); stgB(0, 0, 0); stgB(0, 1, 0);
    if (NT > 1) {
        stgA(1, 0, 64); stgA(1, 1, 64);
        asm volatile("s_waitcnt vmcnt(4)" ::: "memory");
    } else {
        asm volatile("s_waitcnt vmcnt(0)" ::: "memory");
    }
    asm volatile("s_barrier" ::: "memory");

    for (int tt = 0; tt < NT; ++tt) {
        const int R = tt & 1;
        const int S = R ^ 1;
        const size_t k1 = (size_t)(tt + 1) << 6;
        const size_t k2 = (size_t)(tt + 2) << 6;
        const bool p1 = (tt + 1 < NT);
        const bool p2 = (tt + 2 < NT);

        short8 a0[8], a1[8], b0[4], b1[4];

        // ---- phase 1 ----
        #pragma unroll
        for (int i = 0; i < 8; ++i) a0[i] = *(const short8*)&AsB[R * 16384 + abase + i * 1024 + c0];
        #pragma unroll
        for (int j = 0; j < 4; ++j) b0[j] = *(const short8*)&BsB[R * 16384 + bbase + j * 1024 + c0];
        if (p1) stgB(S, 0, k1);
        asm volatile("s_barrier" ::: "memory");
        asm volatile("s_waitcnt lgkmcnt(0)" ::: "memory");
        __builtin_amdgcn_s_setprio(1);
        #pragma unroll
        for (int i = 0; i < 8; ++i) {
            acc[i][0] = mfma16(a0[i], b0[0], acc[i][0]);
            acc[i][1] = mfma16(a0[i], b0[1], acc[i][1]);
        }
        __builtin_amdgcn_s_setprio(0);
        asm volatile("s_barrier" ::: "memory");

        // ---- phase 2 ----
        #pragma unroll
        for (int i = 0; i < 8; ++i) a1[i] = *(const short8*)&AsB[R * 16384 + abase + i * 1024 + c1];
        #pragma unroll
        for (int j = 0; j < 4; ++j) b1[j] = *(const short8*)&BsB[R * 16384 + bbase + j * 1024 + c1];
        if (p1) stgB(S, 1, k1);
        asm volatile("s_barrier" ::: "memory");
        asm volatile("s_waitcnt lgkmcnt(0)" ::: "memory");
        __builtin_amdgcn_s_setprio(1);
        #pragma unroll
        for (int i = 0; i < 8; ++i) {
            acc[i][2] = mfma16(a0[i], b0[2], acc[i][2]);
            acc[i][3] = mfma16(a0[i], b0[3], acc[i][3]);
        }
        __builtin_amdgcn_s_setprio(0);
        asm volatile("s_barrier" ::: "memory");

        // ---- phase 3 ----
        if (p2) stgA(R, 0, k2);
        asm volatile("s_barrier" ::: "memory");
        __builtin_amdgcn_s_setprio(1);
        #pragma unroll
        for (int i = 0; i < 8; ++i) {
            acc[i][0] = mfma16(a1[i], b1[0], acc[i][0]);
            acc[i][1] = mfma16(a1[i], b1[1], acc[i][1]);
        }
        __builtin_amdgcn_s_setprio(0);
        asm volatile("s_barrier" ::: "memory");

        // ---- phase 4 ----
        if (p2) stgA(R, 1, k2);
        asm volatile("s_barrier" ::: "memory");
        __builtin_amdgcn_s_setprio(1);
        #pragma unroll
        for (int i = 0; i < 8; ++i) {
            acc[i][2] = mfma16(a1[i], b1[2], acc[i][2]);
            acc[i][3] = mfma16(a1[i], b1[3], acc[i][3]);
        }
        __builtin_amdgcn_s_setprio(0);
        if (p2) asm volatile("s_waitcnt vmcnt(4)" ::: "memory");
        else    asm volatile("s_waitcnt vmcnt(0)" ::: "memory");
        asm volatile("s_barrier" ::: "memory");
    }

    if (EPI == EPI_BIAS_RES) {
        // legacy direct path (unused instantiation)
        const int r0 = g * 4;
        #pragma unroll
        for (int j = 0; j < 4; ++j) {
            const int gcol = bn * 256 + wn + j * 16 + fl;
            float bval = bf2f(bias[gcol]);
            #pragma unroll
            for (int i = 0; i < 8; ++i) {
                const int growb = bm * 256 + wm + i * 16 + r0;
                #pragma unroll
                for (int r = 0; r < 4; ++r) {
                    const size_t idx = (size_t)(growb + r) * N + gcol;
                    float nh = hf[idx] + acc[i][j][r] + bval;
                    hf[idx] = nh;
                    hb[idx] = f2bf(nh);
                }
            }
        }
    } else {
        // coalesced: stage bf16 tile (256x256, col XOR-swizzled), drain rows
        unsigned short* usc = (unsigned short*)smem;
        asm volatile("s_barrier" ::: "memory");
        #pragma unroll
        for (int j = 0; j < 4; ++j) {
            const int colw = wn + j * 16 + fl;
            float bval = (EPI != EPI_NONE) ? bf2f(bias[bn * 256 + colw]) : 0.f;
            #pragma unroll
            for (int i = 0; i < 8; ++i) {
                #pragma unroll
                for (int r = 0; r < 4; ++r) {
                    const int row = wm + i * 16 + g * 4 + r;
                    float v = acc[i][j][r];
                    if (EPI == EPI_BIAS_RELU) { v += bval; v = v > 0.f ? v : 0.f; }
                    usc[row * 256 + (colw ^ ((row & 7) << 2))] = f2bf(v);
                }
            }
        }
        asm volatile("s_barrier" ::: "memory");
        #pragma unroll
        for (int rr = 0; rr < 32; ++rr) {
            const int rl = wave * 32 + rr;
            const int swz = (rl & 7) << 2;
            shortx4 pk = *(shortx4*)&usc[rl * 256 + ((lane * 4) ^ swz)];
            *(shortx4*)&C[(size_t)(bm * 256 + rl) * N + bn * 256 + lane * 4] = pk;
        }
    }
}

// ---------------------------------------------------------------------------
// 128x256 tile, BK=64, 8-phase counted-vmcnt. FFN2 (512 blocks = 2 rounds).
// NEW: coalesced epilogue — f32 acc staged in LDS (two 64-row halves,
// stride-260 pad), drained as full 1KB f32 rows: hf read/write and hb write
// all become 64-lane contiguous segments.
// ---------------------------------------------------------------------------
template<int EPI>
__global__ __launch_bounds__(512) void gemm128x256_bt(
    const unsigned short* __restrict__ A,
    const unsigned short* __restrict__ Bmat,
    unsigned short* __restrict__ C,
    const unsigned short* __restrict__ bias,
    float* __restrict__ hf,
    unsigned short* __restrict__ hb,
    int N, int K)
{
    __shared__ __align__(16) unsigned char smem[98304];
    unsigned short* AsB = (unsigned short*)smem;            // [2][8192]  (32 KB)
    unsigned short* BsB = (unsigned short*)(smem + 32768);  // [2][16384] (64 KB)

    const int t = threadIdx.x;           // 0..511
    const int lane = t & 63;
    const int wave = t >> 6;             // 0..7
    const int bm = blockIdx.x;
    const int bn = blockIdx.y;

    const int wm = (wave >> 2) * 64;
    const int wn = (wave & 3) * 64;

    const int srow = t >> 3;                               // 0..63
    const int scol = ((t & 7) ^ (srow & 7)) * 8;
    const unsigned short* Ag = A + (size_t)(bm * 128 + srow) * K + scol;
    const unsigned short* Bg = Bmat + (size_t)(bn * 256 + srow) * K + scol;
    const size_t rows64 = (size_t)64 * K;

    const int fl = lane & 15;
    const int g = lane >> 4;
    const int s7 = fl & 7;
    const int c0 = (g ^ s7) * 8;
    const int c1 = ((4 + g) ^ s7) * 8;
    const int abase = (wm + fl) * 64;
    const int bbase = (wn + fl) * 64;

    floatx4 acc[4][4];
    #pragma unroll
    for (int i = 0; i < 4; ++i)
        #pragma unroll
        for (int j = 0; j < 4; ++j) {
            acc[i][j][0] = 0.f; acc[i][j][1] = 0.f;
            acc[i][j][2] = 0.f; acc[i][j][3] = 0.f;
        }

    auto stgA = [&](int buf, size_t koff) {
        const unsigned short* s = Ag + koff;
        unsigned short* d = &AsB[buf * 8192 + t * 8];
        async_cp16(s, d);
        async_cp16(s + rows64, d + 4096);
    };
    auto stgB = [&](int buf, int h, size_t koff) {
        const unsigned short* s = Bg + (size_t)(h * 128) * K + koff;
        unsigned short* d = &BsB[buf * 16384 + h * 8192 + t * 8];
        async_cp16(s, d);
        async_cp16(s + rows64, d + 4096);
    };

    const int NT = K >> 6;

    stgA(0, 0); stgB(0, 0, 0); stgB(0, 1, 0);
    if (NT > 1) {
        stgA(1, 64);
        asm volatile("s_waitcnt vmcnt(2)" ::: "memory");
    } else {
        asm volatile("s_waitcnt vmcnt(0)" ::: "memory");
    }
    asm volatile("s_barrier" ::: "memory");

    for (int tt = 0; tt < NT; ++tt) {
        const int R = tt & 1;
        const int S = R ^ 1;
        const size_t k1 = (size_t)(tt + 1) << 6;
        const size_t k2 = (size_t)(tt + 2) << 6;
        const bool p1 = (tt + 1 < NT);
        const bool p2 = (tt + 2 < NT);

        short8 a0[4], a1[4], b0[4], b1[4];

        // ---- phase 1 ----
        #pragma unroll
        for (int i = 0; i < 4; ++i) a0[i] = *(const short8*)&AsB[R * 8192 + abase + i * 1024 + c0];
        #pragma unroll
        for (int j = 0; j < 4; ++j) b0[j] = *(const short8*)&BsB[R * 16384 + bbase + j * 1024 + c0];
        if (p1) stgB(S, 0, k1);
        asm volatile("s_barrier" ::: "memory");
        asm volatile("s_waitcnt lgkmcnt(0)" ::: "memory");
        __builtin_amdgcn_s_setprio(1);
        #pragma unroll
        for (int i = 0; i < 4; ++i) {
            acc[i][0] = mfma16(a0[i], b0[0], acc[i][0]);
            acc[i][1] = mfma16(a0[i], b0[1], acc[i][1]);
        }
        __builtin_amdgcn_s_setprio(0);
        asm volatile("s_barrier" ::: "memory");

        // ---- phase 2 ----
        #pragma unroll
        for (int i = 0; i < 4; ++i) a1[i] = *(const short8*)&AsB[R * 8192 + abase + i * 1024 + c1];
        #pragma unroll
        for (int j = 0; j < 4; ++j) b1[j] = *(const short8*)&BsB[R * 16384 + bbase + j * 1024 + c1];
        if (p1) stgB(S, 1, k1);
        asm volatile("s_barrier" ::: "memory");
        asm volatile("s_waitcnt lgkmcnt(0)" ::: "memory");   // all buf-R reads retired
        __builtin_amdgcn_s_setprio(1);
        #pragma unroll
        for (int i = 0; i < 4; ++i) {
            acc[i][2] = mfma16(a0[i], b0[2], acc[i][2]);
            acc[i][3] = mfma16(a0[i], b0[3], acc[i][3]);
        }
        __builtin_amdgcn_s_setprio(0);
        asm volatile("s_barrier" ::: "memory");

        // ---- phase 3 ----
        if (p2) stgA(R, k2);
        asm volatile("s_barrier" ::: "memory");
        __builtin_amdgcn_s_setprio(1);
        #pragma unroll
        for (int i = 0; i < 4; ++i) {
            acc[i][0] = mfma16(a1[i], b1[0], acc[i][0]);
            acc[i][1] = mfma16(a1[i], b1[1], acc[i][1]);
        }
        __builtin_amdgcn_s_setprio(0);
        asm volatile("s_barrier" ::: "memory");

        // ---- phase 4 ----
        __builtin_amdgcn_s_setprio(1);
        #pragma unroll
        for (int i = 0; i < 4; ++i) {
            acc[i][2] = mfma16(a1[i], b1[2], acc[i][2]);
            acc[i][3] = mfma16(a1[i], b1[3], acc[i][3]);
        }
        __builtin_amdgcn_s_setprio(0);
        if (p2) asm volatile("s_waitcnt vmcnt(2)" ::: "memory");
        else    asm volatile("s_waitcnt vmcnt(0)" ::: "memory");
        asm volatile("s_barrier" ::: "memory");
    }

    // coalesced epilogue: two 64-row halves via f32 LDS scratch [64][260]
    float* fsc = (float*)smem;
    for (int h = 0; h < 2; ++h) {
        asm volatile("s_barrier" ::: "memory");
        if ((wave >> 2) == h) {
            #pragma unroll
            for (int i = 0; i < 4; ++i)
                #pragma unroll
                for (int j = 0; j < 4; ++j)
                    #pragma unroll
                    for (int r = 0; r < 4; ++r)
                        fsc[(i * 16 + g * 4 + r) * 260 + wn + j * 16 + fl] = acc[i][j][r];
        }
        asm volatile("s_barrier" ::: "memory");
        #pragma unroll
        for (int rr = 0; rr < 8; ++rr) {
            const int rl = wave * 8 + rr;
            const int grow = bm * 128 + h * 64 + rl;
            const int gcol = bn * 256 + lane * 4;
            const size_t idx = (size_t)grow * N + gcol;
            floatx4 v = *(floatx4*)&fsc[rl * 260 + lane * 4];
            float b0v = 0.f, b1v = 0.f, b2v = 0.f, b3v = 0.f;
            if (EPI != EPI_NONE) {
                b0v = bf2f(bias[gcol]);     b1v = bf2f(bias[gcol + 1]);
                b2v = bf2f(bias[gcol + 2]); b3v = bf2f(bias[gcol + 3]);
            }
            if (EPI == EPI_BIAS_RES) {
                floatx4 hv = *(const floatx4*)&hf[idx];
                floatx4 nh;
                nh[0] = hv[0] + v[0] + b0v; nh[1] = hv[1] + v[1] + b1v;
                nh[2] = hv[2] + v[2] + b2v; nh[3] = hv[3] + v[3] + b3v;
                *(floatx4*)&hf[idx] = nh;
                shortx4 pk;
                pk[0] = (short)f2bf(nh[0]); pk[1] = (short)f2bf(nh[1]);
                pk[2] = (short)f2bf(nh[2]); pk[3] = (short)f2bf(nh[3]);
                *(shortx4*)&hb[idx] = pk;
            } else {
                float v0 = v[0], v1 = v[1], v2 = v[2], v3 = v[3];
                if (EPI == EPI_BIAS_RELU) {
                    v0 += b0v; v1 += b1v; v2 += b2v; v3 += b3v;
                    v0 = v0 > 0.f ? v0 : 0.f; v1 = v1 > 0.f ? v1 : 0.f;
                    v2 = v2 > 0.f ? v2 : 0.f; v3 = v3 > 0.f ? v3 : 0.f;
                }
                shortx4 pk;
                pk[0] = (short)f2bf(v0); pk[1] = (short)f2bf(v1);
                pk[2] = (short)f2bf(v2); pk[3] = (short)f2bf(v3);
                *(shortx4*)&C[idx] = pk;
            }
        }
    }
}

// MFMA flash attention (validated round 4). blockIdx = pair*4 + qquarter.
__global__ __launch_bounds__(128) void attn_mfma(
    const unsigned short* __restrict__ Q,
    const unsigned short* __restrict__ Kx,
    const unsigned short* __restrict__ Vx,
    const float* __restrict__ maskf,
    unsigned short* __restrict__ Out)
{
    __shared__ __align__(16) unsigned short Vt[16 * 520];
    __shared__ __align__(16) unsigned short Pb[2][64 * 40];
    __shared__ float Ms[512];
    __shared__ float cnt_s;

    const int t = threadIdx.x;
    const int lane = t & 63;
    const int wave = t >> 6;
    const int p = blockIdx.x >> 2;
    const int qq = blockIdx.x & 3;
    const int b2 = p & 31;
    const int h2 = p >> 5;
    const int fm = lane & 15;
    const int g = lane >> 4;

    const unsigned short* Qg = Q + (size_t)p * 8192;
    const unsigned short* Kg = Kx + (size_t)p * 8192;
    const unsigned short* Vg = Vx + (size_t)p * 8192;

    #pragma unroll
    for (int rr = 0; rr < 4; ++rr) {
        const int row = t * 4 + rr;
        short8 v0 = *(const short8*)&Vg[row * 16];
        short8 v1 = *(const short8*)&Vg[row * 16 + 8];
        #pragma unroll
        for (int d = 0; d < 8; ++d) Vt[d * 520 + row] = (unsigned short)v0[d];
        #pragma unroll
        for (int d = 0; d < 8; ++d) Vt[(d + 8) * 520 + row] = (unsigned short)v1[d];
    }
    if (t == 0) cnt_s = 0.f;
    __syncthreads();
    float pc = 0.f;
    #pragma unroll
    for (int it = 0; it < 4; ++it) {
        int i = it * 128 + t;
        float mv = maskf[b2 * 512 + i];
        Ms[i] = mv; pc += mv;
    }
    atomicAdd(&cnt_s, pc);
    __syncthreads();
    const float cnt = cnt_s;

    const int qbase = qq * 128 + wave * 64;
    short8 qf[4];
    #pragma unroll
    for (int i = 0; i < 4; ++i) {
        short8 z = {0,0,0,0,0,0,0,0};
        if (g < 2) z = *(const short8*)&Qg[(qbase + i * 16 + fm) * 16 + g * 8];
        qf[i] = z;
    }

    float m_[4][4], l_[4][4];
    floatx4 O[4];
    #pragma unroll
    for (int i = 0; i < 4; ++i) {
        #pragma unroll
        for (int r = 0; r < 4; ++r) { m_[i][r] = -1e30f; l_[i][r] = 0.f; }
        O[i][0] = 0.f; O[i][1] = 0.f; O[i][2] = 0.f; O[i][3] = 0.f;
    }

    unsigned short* Pw = &Pb[wave][0];

    for (int kb = 0; kb < 512; kb += 32) {
        short8 kf0 = {0,0,0,0,0,0,0,0}, kf1 = {0,0,0,0,0,0,0,0};
        if (g < 2) {
            kf0 = *(const short8*)&Kg[(kb + fm) * 16 + g * 8];
            kf1 = *(const short8*)&Kg[(kb + 16 + fm) * 16 + g * 8];
        }
        const float msk0 = Ms[kb + fm];
        const float msk1 = Ms[kb + 16 + fm];

        floatx4 zero4 = {0.f, 0.f, 0.f, 0.f};
        floatx4 s0[4], s1[4];
        #pragma unroll
        for (int i = 0; i < 4; ++i) {
            s0[i] = __builtin_amdgcn_mfma_f32_16x16x32_bf16(qf[i], kf0, zero4, 0, 0, 0);
            s1[i] = __builtin_amdgcn_mfma_f32_16x16x32_bf16(qf[i], kf1, zero4, 0, 0, 0);
        }

        #pragma unroll
        for (int i = 0; i < 4; ++i) {
            #pragma unroll
            for (int r = 0; r < 4; ++r) {
                float a0 = (msk0 != 0.f) ? -1e30f : s0[i][r] * NORM_;
                float a1 = (msk1 != 0.f) ? -1e30f : s1[i][r] * NORM_;
                float mx = fmaxf(a0, a1);
                mx = fmaxf(mx, __shfl_xor(mx, 1));
                mx = fmaxf(mx, __shfl_xor(mx, 2));
                mx = fmaxf(mx, __shfl_xor(mx, 4));
                mx = fmaxf(mx, __shfl_xor(mx, 8));
                const float mo = m_[i][r];
                const float mn = fmaxf(mo, mx);
                const float alpha = __expf(mo - mn);
                float w0 = (msk0 != 0.f) ? 0.f : __expf(a0 - mn);
                float w1 = (msk1 != 0.f) ? 0.f : __expf(a1 - mn);
                float rs = w0 + w1;
                rs += __shfl_xor(rs, 1);
                rs += __shfl_xor(rs, 2);
                rs += __shfl_xor(rs, 4);
                rs += __shfl_xor(rs, 8);
                l_[i][r] = l_[i][r] * alpha + rs;
                m_[i][r] = mn;
                O[i][r] *= alpha;
                const int qloc = i * 16 + g * 4 + r;
                Pw[qloc * 40 + fm] = f2bf(w0);
                Pw[qloc * 40 + 16 + fm] = f2bf(w1);
            }
        }
        asm volatile("s_waitcnt lgkmcnt(0)" ::: "memory");

        short8 vtf = *(const short8*)&Vt[fm * 520 + kb + g * 8];
        #pragma unroll
        for (int i = 0; i < 4; ++i) {
            short8 pf = *(const short8*)&Pw[(i * 16 + fm) * 40 + g * 8];
            O[i] = __builtin_amdgcn_mfma_f32_16x16x32_bf16(pf, vtf, O[i], 0, 0, 0);
        }
    }

    #pragma unroll
    for (int i = 0; i < 4; ++i) {
        #pragma unroll
        for (int r = 0; r < 4; ++r) {
            const float M = fmaxf(m_[i][r], -30.f);
            const float adj = __expf(m_[i][r] - M);
            const float lf = l_[i][r] * adj + cnt * __expf(-30.f - M);
            const float oval = O[i][r] * adj / lf;
            const int n = qbase + i * 16 + g * 4 + r;
            Out[((size_t)(b2 * 512 + n)) * 128 + h2 * 16 + fm] = f2bf(oval);
        }
    }
}

__global__ __launch_bounds__(256) void write_h(const float* __restrict__ hf,
                                               void* __restrict__ out,
                                               const int* __restrict__ flag)
{
    const size_t i = ((size_t)blockIdx.x * 256 + threadIdx.x) * 4;
    floatx4 v = *(const floatx4*)&hf[i];
    if (*flag) {
        *(floatx4*)((float*)out + i) = v;
    } else {
        unsigned int p0 = (unsigned int)f2bf(v[0]) | ((unsigned int)f2bf(v[1]) << 16);
        unsigned int p1 = (unsigned int)f2bf(v[2]) | ((unsigned int)f2bf(v[3]) << 16);
        unsigned int* o = (unsigned int*)((unsigned short*)out + i);
        o[0] = p0; o[1] = p1;
    }
}

__global__ __launch_bounds__(256) void mean_kernel(const float* __restrict__ hf,
                                                   void* __restrict__ out,
                                                   const int* __restrict__ flag)
{
    const int b = blockIdx.x >> 2;
    const int e = ((blockIdx.x & 3) * 256) + threadIdx.x;
    float s = 0.f;
    for (int n = 0; n < 512; ++n) s += hf[((size_t)(b * 512 + n)) * 1024 + e];
    s *= (1.0f / 512.0f);
    const size_t off = (size_t)16384 * 1024 + b * 1024 + e;
    if (*flag) ((float*)out)[off] = s;
    else       ((unsigned short*)out)[off] = f2bf(s);
}

extern "C" void kernel_launch(void* const* d_in, const int* in_sizes, int n_in,
                              void* d_out, int out_size, void* d_ws, size_t ws_size,
                              hipStream_t stream)
{
    const void* x  = d_in[0];
    const unsigned int* mask = (const unsigned int*)d_in[1];

    char* ws = (char*)d_ws;
    float* hf = (float*)ws;                     ws += (size_t)16384 * 1024 * 4;   // 64 MB
    unsigned short* hb = (unsigned short*)ws;   ws += (size_t)16384 * 1024 * 2;   // 32 MB
    char* shared_rg = ws;                       ws += (size_t)16384 * 2048 * 2;   // 64 MB
    unsigned short* act = (unsigned short*)shared_rg;
    unsigned short* q  = (unsigned short*)shared_rg;
    unsigned short* k  = q + (size_t)16384 * 128;
    unsigned short* v  = k + (size_t)16384 * 128;
    unsigned short* ao = v + (size_t)16384 * 128;
    unsigned short* cWq = (unsigned short*)ws;  ws += (size_t)393216 * 2;
    unsigned short* cWk = (unsigned short*)ws;  ws += (size_t)393216 * 2;
    unsigned short* cWv = (unsigned short*)ws;  ws += (size_t)393216 * 2;
    unsigned short* cWo = (unsigned short*)ws;  ws += (size_t)393216 * 2;
    unsigned short* cbo = (unsigned short*)ws;  ws += (size_t)3072 * 2;
    unsigned short* cW1 = (unsigned short*)ws;  ws += (size_t)6291456 * 2;
    unsigned short* cb1 = (unsigned short*)ws;  ws += (size_t)6144 * 2;
    unsigned short* cW2 = (unsigned short*)ws;  ws += (size_t)6291456 * 2;
    unsigned short* cb2 = (unsigned short*)ws;  ws += (size_t)3072 * 2;
    float* maskf = (float*)ws;                  ws += (size_t)16384 * 4;
    int* flag = (int*)ws;                       ws += 256;

    detect_dtype<<<1, 256, 0, stream>>>((const unsigned int*)x, flag);

    auto conv = [&](const void* s, unsigned short* d, int n) {
        conv_to_bf16<<<(n / 8 + 255) / 256, 256, 0, stream>>>(s, d, n, flag);
    };
    conv(d_in[2], cWq, 393216);
    conv(d_in[3], cWk, 393216);
    conv(d_in[4], cWv, 393216);
    conv(d_in[5], cWo, 393216);
    conv(d_in[6], cbo, 3072);
    conv(d_in[7], cW1, 6291456);
    conv(d_in[8], cb1, 6144);
    conv(d_in[9], cW2, 6291456);
    conv(d_in[10], cb2, 3072);

    mask_expand<<<64, 256, 0, stream>>>(mask, maskf);
    init_h<<<8192, 256, 0, stream>>>(x, hf, hb, flag);

    for (int l = 0; l < 3; ++l) {
        const unsigned short* wq  = cWq + (size_t)l * 131072;
        const unsigned short* wk  = cWk + (size_t)l * 131072;
        const unsigned short* wv  = cWv + (size_t)l * 131072;
        const unsigned short* wo  = cWo + (size_t)l * 131072;
        const unsigned short* bol = cbo + (size_t)l * 1024;
        const unsigned short* w1  = cW1 + (size_t)l * 2097152;
        const unsigned short* b1l = cb1 + (size_t)l * 2048;
        const unsigned short* w2  = cW2 + (size_t)l * 2097152;
        const unsigned short* b2l = cb2 + (size_t)l * 1024;

        gemm_bt<EPI_NONE><<<dim3(128, 1, 3), 256, 0, stream>>>(
            hb, wq, wk, wv, q, k, v, nullptr, nullptr, nullptr, 128, 1024);
        attn_mfma<<<1024, 128, 0, stream>>>(q, k, v, maskf, ao);
        gemm_bt<EPI_BIAS_RES><<<dim3(128, 8, 1), 256, 0, stream>>>(
            ao, wo, wo, wo, nullptr, nullptr, nullptr, bol, hf, hb, 1024, 128);
        // FFN1: 256^2 8-phase + coalesced C epilogue
        gemm256_bt<EPI_BIAS_RELU><<<dim3(64, 8, 1), 512, 0, stream>>>(
            hb, w1, act, b1l, nullptr, nullptr, 2048, 1024);
        // FFN2: 128x256 8-phase + coalesced hf/hb epilogue
        gemm128x256_bt<EPI_BIAS_RES><<<dim3(128, 4, 1), 512, 0, stream>>>(
            act, w2, nullptr, b2l, hf, hb, 1024, 2048);
    }

    write_h<<<16384, 256, 0, stream>>>(hf, d_out, flag);
    mean_kernel<<<128, 256, 0, stream>>>(hf, d_out, flag);
}

// Round 17
// 1113.800 us; speedup vs baseline: 1.4781x; 1.0470x over previous
//
#include <hip/hip_runtime.h>
#include <stdint.h>

// Problem: B=32, N=512, E=1024, H=8, L=3, FF=2048, KD=128, DK=16
// r15 confirmed: scattered MFMA-layout epilogue stores cost 1.6x WRITE
// amplification; LDS-bounce to full-row segments removes it (FFN2 153->98MB,
// 114.7->101us). This round: same fix for Wo's residual epilogue (gemm_bt
// EPI_BIAS_RES), the remaining kernel with the scattered hf/hb pattern.

typedef __attribute__((ext_vector_type(8))) short short8;
typedef __attribute__((ext_vector_type(4))) short shortx4;
typedef __attribute__((ext_vector_type(4))) float floatx4;

#define NORM_ 0.08838834764831845f   // 1/sqrt(128)

__device__ __forceinline__ float bf2f(unsigned short u) {
    union { unsigned int i; float f; } x; x.i = ((unsigned int)u) << 16; return x.f;
}
__device__ __forceinline__ unsigned short f2bf(float f) {  // RNE
    union { float f; unsigned int i; } x; x.f = f;
    unsigned int u = x.i;
    u += 0x7FFFu + ((u >> 16) & 1u);
    return (unsigned short)(u >> 16);
}
__device__ __forceinline__ void async_cp16(const void* g, void* l) {
    __builtin_amdgcn_global_load_lds((const __attribute__((address_space(1))) void*)g,
                                     (__attribute__((address_space(3))) void*)l, 16, 0, 0);
}
__device__ __forceinline__ floatx4 mfma16(short8 a, short8 b, floatx4 c) {
    return __builtin_amdgcn_mfma_f32_16x16x32_bf16(a, b, c, 0, 0, 0);
}

// ---- transport dtype detection -------------------------------------------
__global__ __launch_bounds__(256) void detect_dtype(const unsigned int* __restrict__ x,
                                                    int* __restrict__ flag)
{
    __shared__ int good, bad;
    if (threadIdx.x == 0) { good = 0; bad = 0; }
    __syncthreads();
    int g = 0, b = 0;
    for (int i = threadIdx.x; i < 4096; i += 256) {
        unsigned int lo = x[i] & 0xFFFFu;
        if (lo != 0u) {
            unsigned int e = (lo >> 7) & 0xFFu;
            if (e >= 90u && e <= 145u) ++g; else ++b;
        }
    }
    atomicAdd(&good, g); atomicAdd(&bad, b);
    __syncthreads();
    if (threadIdx.x == 0) *flag = (bad > good) ? 1 : 0;   // 1 = f32 transport
}

__global__ __launch_bounds__(256) void conv_to_bf16(const void* __restrict__ src,
                                                    unsigned short* __restrict__ dst,
                                                    int n, const int* __restrict__ flag)
{
    const int i = (blockIdx.x * 256 + threadIdx.x) * 8;
    if (i >= n) return;
    if (*flag) {
        const float* s = (const float*)src + i;
        floatx4 a = *(const floatx4*)s;
        floatx4 b = *(const floatx4*)(s + 4);
        short8 o;
        o[0] = (short)f2bf(a[0]); o[1] = (short)f2bf(a[1]);
        o[2] = (short)f2bf(a[2]); o[3] = (short)f2bf(a[3]);
        o[4] = (short)f2bf(b[0]); o[5] = (short)f2bf(b[1]);
        o[6] = (short)f2bf(b[2]); o[7] = (short)f2bf(b[3]);
        *(short8*)(dst + i) = o;
    } else {
        *(short8*)(dst + i) = *(const short8*)((const unsigned short*)src + i);
    }
}

__global__ __launch_bounds__(256) void init_h(const void* __restrict__ x,
                                              float* __restrict__ hf,
                                              unsigned short* __restrict__ hb,
                                              const int* __restrict__ flag)
{
    const size_t i = ((size_t)blockIdx.x * 256 + threadIdx.x) * 8;
    if (*flag) {
        const float* s = (const float*)x + i;
        floatx4 a = *(const floatx4*)s;
        floatx4 b = *(const floatx4*)(s + 4);
        short8 o;
        o[0] = (short)f2bf(a[0]); o[1] = (short)f2bf(a[1]);
        o[2] = (short)f2bf(a[2]); o[3] = (short)f2bf(a[3]);
        o[4] = (short)f2bf(b[0]); o[5] = (short)f2bf(b[1]);
        o[6] = (short)f2bf(b[2]); o[7] = (short)f2bf(b[3]);
        *(short8*)(hb + i) = o;
        *(floatx4*)(hf + i) = a;
        *(floatx4*)(hf + i + 4) = b;
    } else {
        short8 v = *(const short8*)((const unsigned short*)x + i);
        *(short8*)(hb + i) = v;
        #pragma unroll
        for (int e = 0; e < 8; ++e) hf[i + e] = bf2f((unsigned short)v[e]);
    }
}

__global__ __launch_bounds__(256) void mask_expand(const unsigned int* __restrict__ mraw,
                                                   float* __restrict__ maskf)
{
    __shared__ unsigned int r[4];
    if (threadIdx.x < 4) r[threadIdx.x] = 0;
    __syncthreads();
    unsigned int gt1 = 0, badb = 0, badh = 0, lo3f = 0;
    for (int i = threadIdx.x; i < 4096; i += 256) {
        unsigned int w = mraw[i];
        if (w > 1u) gt1 = 1;
        if (w & 0xFEFEFEFEu) badb = 1;
        unsigned int lo = w & 0xFFFFu, hi = w >> 16;
        if ((lo != 0u && lo != 0x3F80u) || (hi != 0u && hi != 0x3F80u)) badh = 1;
        if (lo == 0x3F80u) lo3f = 1;
    }
    if (gt1) atomicOr(&r[0], 1u);
    if (badb) atomicOr(&r[1], 1u);
    if (badh) atomicOr(&r[2], 1u);
    if (lo3f) atomicOr(&r[3], 1u);
    __syncthreads();
    int cls;
    if (!r[0]) cls = 0;
    else if (!r[1]) cls = 1;
    else if (!r[2]) cls = r[3] ? 2 : 3;
    else cls = 0;

    const int gid = blockIdx.x * 256 + threadIdx.x;
    bool m;
    if (cls == 0)      m = ((const int*)mraw)[gid] != 0;
    else if (cls == 1) m = ((const unsigned char*)mraw)[gid] != 0;
    else if (cls == 2) m = ((const unsigned short*)mraw)[gid] != 0;
    else               m = mraw[gid] != 0u;
    maskf[gid] = m ? 1.0f : 0.0f;
}

enum { EPI_NONE = 0, EPI_BIAS_RELU = 1, EPI_BIAS_RES = 2 };

// ---------------------------------------------------------------------------
// 128x128 tile kernel — QKV (N=128, EPI_NONE) and Wo (K=128, EPI_BIAS_RES).
// NEW: EPI_BIAS_RES path gets the r15-proven coalesced LDS-bounce epilogue
// (two 64-row halves via f32 scratch [64][132]); hf r/w -> 512B row segments,
// hb -> 256B row segments. EPI_NONE path unchanged (control).
// ---------------------------------------------------------------------------
template<int EPI>
__global__ __launch_bounds__(256) void gemm_bt(
    const unsigned short* __restrict__ A,
    const unsigned short* __restrict__ Bq,
    const unsigned short* __restrict__ Bk,
    const unsigned short* __restrict__ Bv,
    unsigned short* __restrict__ Cq,
    unsigned short* __restrict__ Ck,
    unsigned short* __restrict__ Cv,
    const unsigned short* __restrict__ bias,
    float* __restrict__ hf,
    unsigned short* __restrict__ hb,
    int N, int K)
{
    constexpr int BK = 64;
    __shared__ __align__(16) unsigned char smem[65536];
    unsigned short* AsB = (unsigned short*)smem;            // [2][8192] (32 KB)
    unsigned short* BsB = (unsigned short*)(smem + 32768);  // [2][8192] (32 KB)

    const int t = threadIdx.x;
    const int lane = t & 63;
    const int wave = t >> 6;
    const int bm = blockIdx.x;
    const int bn = blockIdx.y;
    const int bz = blockIdx.z;

    const unsigned short* Bmat = (bz == 0) ? Bq : ((bz == 1) ? Bk : Bv);
    unsigned short* C = (bz == 0) ? Cq : ((bz == 1) ? Ck : Cv);

    const int wm = (wave >> 1) * 64;
    const int wn = (wave & 1) * 64;

    const int srow = t >> 3;                               // 0..31
    const int scol = (((t & 7) ^ ((t >> 3) & 7)) * 8);     // swizzled source col
    const unsigned short* Ag = A + (size_t)(bm * 128 + srow) * K + scol;
    const unsigned short* Bg = Bmat + (size_t)(bn * 128 + srow) * K + scol;
    const size_t gstep = (size_t)32 * K;                   // 32 rows per round

    const int fl = lane & 15;
    const int g = lane >> 4;
    const int s7 = fl & 7;
    const int swz0 = (g ^ s7) * 8;          // ks = 0 chunk
    const int swz1 = ((g + 4) ^ s7) * 8;    // ks = 32 chunk
    int aoff[4], boff[4];
    #pragma unroll
    for (int i = 0; i < 4; ++i) {
        aoff[i] = (wm + i * 16 + fl) * BK;
        boff[i] = (wn + i * 16 + fl) * BK;
    }

    floatx4 acc[4][4];
    #pragma unroll
    for (int i = 0; i < 4; ++i)
        #pragma unroll
        for (int j = 0; j < 4; ++j) {
            acc[i][j][0] = 0.f; acc[i][j][1] = 0.f;
            acc[i][j][2] = 0.f; acc[i][j][3] = 0.f;
        }

    const int NT = K / BK;

    #pragma unroll
    for (int r = 0; r < 4; ++r) {
        async_cp16(Ag + r * gstep, &AsB[t * 8 + r * 2048]);
        async_cp16(Bg + r * gstep, &BsB[t * 8 + r * 2048]);
    }

    for (int it = 0; it < NT; ++it) {
        const int cur = it & 1;
        if (it + 1 < NT) {
            const int nxt = cur ^ 1;
            const size_t koff = (size_t)(it + 1) * BK;
            #pragma unroll
            for (int r = 0; r < 4; ++r) {
                async_cp16(Ag + koff + r * gstep, &AsB[nxt * 8192 + t * 8 + r * 2048]);
                async_cp16(Bg + koff + r * gstep, &BsB[nxt * 8192 + t * 8 + r * 2048]);
            }
            asm volatile("s_waitcnt vmcnt(8)" ::: "memory");
        } else {
            asm volatile("s_waitcnt vmcnt(0)" ::: "memory");
        }
        asm volatile("s_barrier" ::: "memory");

        #pragma unroll
        for (int ks = 0; ks < 2; ++ks) {
            const int sw = ks ? swz1 : swz0;
            short8 af[4], bfr[4];
            #pragma unroll
            for (int i = 0; i < 4; ++i) af[i] = *(const short8*)&AsB[cur * 8192 + aoff[i] + sw];
            #pragma unroll
            for (int j = 0; j < 4; ++j) bfr[j] = *(const short8*)&BsB[cur * 8192 + boff[j] + sw];
            #pragma unroll
            for (int i = 0; i < 4; ++i)
                #pragma unroll
                for (int j = 0; j < 4; ++j)
                    acc[i][j] = __builtin_amdgcn_mfma_f32_16x16x32_bf16(af[i], bfr[j], acc[i][j], 0, 0, 0);
        }
        if (it + 1 < NT)
            asm volatile("s_barrier" ::: "memory");
    }

    if (EPI == EPI_BIAS_RES) {
        // coalesced residual epilogue: two 64-row halves via f32 scratch [64][132]
        float* fsc = (float*)smem;
        for (int h = 0; h < 2; ++h) {
            asm volatile("s_barrier" ::: "memory");
            if ((wave >> 1) == h) {
                #pragma unroll
                for (int i = 0; i < 4; ++i)
                    #pragma unroll
                    for (int j = 0; j < 4; ++j)
                        #pragma unroll
                        for (int r = 0; r < 4; ++r)
                            fsc[(i * 16 + g * 4 + r) * 132 + wn + j * 16 + fl] = acc[i][j][r];
            }
            asm volatile("s_barrier" ::: "memory");
            #pragma unroll
            for (int rr = 0; rr < 8; ++rr) {
                const int rl = rr * 8 + (t >> 5);       // 0..63
                const int cc = (t & 31) * 4;            // 0..124
                const int grow = bm * 128 + h * 64 + rl;
                const int gcol = bn * 128 + cc;
                const size_t idx = (size_t)grow * N + gcol;
                floatx4 v = *(floatx4*)&fsc[rl * 132 + cc];
                float b0v = bf2f(bias[gcol]),     b1v = bf2f(bias[gcol + 1]);
                float b2v = bf2f(bias[gcol + 2]), b3v = bf2f(bias[gcol + 3]);
                floatx4 hv = *(const floatx4*)&hf[idx];
                floatx4 nh;
                nh[0] = hv[0] + v[0] + b0v; nh[1] = hv[1] + v[1] + b1v;
                nh[2] = hv[2] + v[2] + b2v; nh[3] = hv[3] + v[3] + b3v;
                *(floatx4*)&hf[idx] = nh;
                shortx4 pk;
                pk[0] = (short)f2bf(nh[0]); pk[1] = (short)f2bf(nh[1]);
                pk[2] = (short)f2bf(nh[2]); pk[3] = (short)f2bf(nh[3]);
                *(shortx4*)&hb[idx] = pk;
            }
        }
    } else {
        const int r0 = (lane >> 4) * 4;
        #pragma unroll
        for (int j = 0; j < 4; ++j) {
            const int gcol = bn * 128 + wn + j * 16 + fl;
            float bval = 0.f;
            if (EPI != EPI_NONE) bval = bf2f(bias[gcol]);
            #pragma unroll
            for (int i = 0; i < 4; ++i) {
                const int growb = bm * 128 + wm + i * 16 + r0;
                #pragma unroll
                for (int r = 0; r < 4; ++r) {
                    const size_t idx = (size_t)(growb + r) * N + gcol;
                    float v = acc[i][j][r];
                    if (EPI == EPI_NONE) {
                        C[idx] = f2bf(v);
                    } else {
                        v += bval;
                        v = v > 0.f ? v : 0.f;
                        C[idx] = f2bf(v);
                    }
                }
            }
        }
    }
}

// ---------------------------------------------------------------------------
// 256x256 tile, BK=64, 8-phase counted-vmcnt. FFN1 (512 blocks = 2 rounds).
// Coalesced bf16 C epilogue (r15-verified).
// ---------------------------------------------------------------------------
template<int EPI>
__global__ __launch_bounds__(512) void gemm256_bt(
    const unsigned short* __restrict__ A,
    const unsigned short* __restrict__ Bmat,
    unsigned short* __restrict__ C,
    const unsigned short* __restrict__ bias,
    float* __restrict__ hf,
    unsigned short* __restrict__ hb,
    int N, int K)
{
    __shared__ __align__(16) unsigned char smem[131072];
    unsigned short* AsB = (unsigned short*)smem;            // [2][16384]
    unsigned short* BsB = (unsigned short*)(smem + 65536);  // [2][16384]

    const int t = threadIdx.x;           // 0..511
    const int lane = t & 63;
    const int wave = t >> 6;             // 0..7
    const int bm = blockIdx.x;
    const int bn = blockIdx.y;

    const int wm = (wave >> 2) * 128;
    const int wn = (wave & 3) * 64;

    const int srow = t >> 3;                               // 0..63
    const int scol = ((t & 7) ^ (srow & 7)) * 8;
    const unsigned short* Ag = A + (size_t)(bm * 256 + srow) * K + scol;
    const unsigned short* Bg = Bmat + (size_t)(bn * 256 + srow) * K + scol;
    const size_t rows64 = (size_t)64 * K;

    const int fl = lane & 15;
    const int g = lane >> 4;
    const int s7 = fl & 7;
    const int c0 = (g ^ s7) * 8;
    const int c1 = ((4 + g) ^ s7) * 8;
    const int abase = (wm + fl) * 64;
    const int bbase = (wn + fl) * 64;

    floatx4 acc[8][4];
    #pragma unroll
    for (int i = 0; i < 8; ++i)
        #pragma unroll
        for (int j = 0; j < 4; ++j) {
            acc[i][j][0] = 0.f; acc[i][j][1] = 0.f;
            acc[i][j][2] = 0.f; acc[i][j][3] = 0.f;
        }

    auto stgA = [&](int buf, int h, size_t koff) {
        const unsigned short* s = Ag + (size_t)(h * 128) * K + koff;
        unsigned short* d = &AsB[buf * 16384 + h * 8192 + t * 8];
        async_cp16(s, d);
        async_cp16(s + rows64, d + 4096);
    };
    auto stgB = [&](int buf, int h, size_t koff) {
        const unsigned short* s = Bg + (size_t)(h * 128) * K + koff;
        unsigned short* d = &BsB[buf * 16384 + h * 8192 + t * 8];
        async_cp16(s, d);
        async_cp16(s + rows64, d + 4096);
    };

    const int NT = K >> 6;

    stgA(0, 0, 0); stgA(0, 1, 0); stgB(0, 0, 0); stgB(0, 1, 0);
    if (NT > 1) {
        stgA(1, 0, 64); stgA(1, 1, 64);
        asm volatile("s_waitcnt vmcnt(4)" ::: "memory");
    } else {
        asm volatile("s_waitcnt vmcnt(0)" ::: "memory");
    }
    asm volatile("s_barrier" ::: "memory");

    for (int tt = 0; tt < NT; ++tt) {
        const int R = tt & 1;
        const int S = R ^ 1;
        const size_t k1 = (size_t)(tt + 1) << 6;
        const size_t k2 = (size_t)(tt + 2) << 6;
        const bool p1 = (tt + 1 < NT);
        const bool p2 = (tt + 2 < NT);

        short8 a0[8], a1[8], b0[4], b1[4];

        // ---- phase 1 ----
        #pragma unroll
        for (int i = 0; i < 8; ++i) a0[i] = *(const short8*)&AsB[R * 16384 + abase + i * 1024 + c0];
        #pragma unroll
        for (int j = 0; j < 4; ++j) b0[j] = *(const short8*)&BsB[R * 16384 + bbase + j * 1024 + c0];
        if (p1) stgB(S, 0, k1);
        asm volatile("s_barrier" ::: "memory");
        asm volatile("s_waitcnt lgkmcnt(0)" ::: "memory");
        __builtin_amdgcn_s_setprio(1);
        #pragma unroll
        for (int i = 0; i < 8; ++i) {
            acc[i][0] = mfma16(a0[i], b0[0], acc[i][0]);
            acc[i][1] = mfma16(a0[i], b0[1], acc[i][1]);
        }
        __builtin_amdgcn_s_setprio(0);
        asm volatile("s_barrier" ::: "memory");

        // ---- phase 2 ----
        #pragma unroll
        for (int i = 0; i < 8; ++i) a1[i] = *(const short8*)&AsB[R * 16384 + abase + i * 1024 + c1];
        #pragma unroll
        for (int j = 0; j < 4; ++j) b1[j] = *(const short8*)&BsB[R * 16384 + bbase + j * 1024 + c1];
        if (p1) stgB(S, 1, k1);
        asm volatile("s_barrier" ::: "memory");
        asm volatile("s_waitcnt lgkmcnt(0)" ::: "memory");
        __builtin_amdgcn_s_setprio(1);
        #pragma unroll
        for (int i = 0; i < 8; ++i) {
            acc[i][2] = mfma16(a0[i], b0[2], acc[i][2]);
            acc[i][3] = mfma16(a0[i], b0[3], acc[i][3]);
        }
        __builtin_amdgcn_s_setprio(0);
        asm volatile("s_barrier" ::: "memory");

        // ---- phase 3 ----
        if (p2) stgA(R, 0, k2);
        asm volatile("s_barrier" ::: "memory");
        __builtin_amdgcn_s_setprio(1);
        #pragma unroll
        for (int i = 0; i < 8; ++i) {
            acc[i][0] = mfma16(a1[i], b1[0], acc[i][0]);
            acc[i][1] = mfma16(a1[i], b1[1], acc[i][1]);
        }
        __builtin_amdgcn_s_setprio(0);
        asm volatile("s_barrier" ::: "memory");

        // ---- phase 4 ----
        if (p2) stgA(R, 1, k2);
        asm volatile("s_barrier" ::: "memory");
        __builtin_amdgcn_s_setprio(1);
        #pragma unroll
        for (int i = 0; i < 8; ++i) {
            acc[i][2] = mfma16(a1[i], b1[2], acc[i][2]);
            acc[i][3] = mfma16(a1[i], b1[3], acc[i][3]);
        }
        __builtin_amdgcn_s_setprio(0);
        if (p2) asm volatile("s_waitcnt vmcnt(4)" ::: "memory");
        else    asm volatile("s_waitcnt vmcnt(0)" ::: "memory");
        asm volatile("s_barrier" ::: "memory");
    }

    if (EPI == EPI_BIAS_RES) {
        // legacy direct path (unused instantiation)
        const int r0 = g * 4;
        #pragma unroll
        for (int j = 0; j < 4; ++j) {
            const int gcol = bn * 256 + wn + j * 16 + fl;
            float bval = bf2f(bias[gcol]);
            #pragma unroll
            for (int i = 0; i < 8; ++i) {
                const int growb = bm * 256 + wm + i * 16 + r0;
                #pragma unroll
                for (int r = 0; r < 4; ++r) {
                    const size_t idx = (size_t)(growb + r) * N + gcol;
                    float nh = hf[idx] + acc[i][j][r] + bval;
                    hf[idx] = nh;
                    hb[idx] = f2bf(nh);
                }
            }
        }
    } else {
        // coalesced: stage bf16 tile (256x256, col XOR-swizzled), drain rows
        unsigned short* usc = (unsigned short*)smem;
        asm volatile("s_barrier" ::: "memory");
        #pragma unroll
        for (int j = 0; j < 4; ++j) {
            const int colw = wn + j * 16 + fl;
            float bval = (EPI != EPI_NONE) ? bf2f(bias[bn * 256 + colw]) : 0.f;
            #pragma unroll
            for (int i = 0; i < 8; ++i) {
                #pragma unroll
                for (int r = 0; r < 4; ++r) {
                    const int row = wm + i * 16 + g * 4 + r;
                    float v = acc[i][j][r];
                    if (EPI == EPI_BIAS_RELU) { v += bval; v = v > 0.f ? v : 0.f; }
                    usc[row * 256 + (colw ^ ((row & 7) << 2))] = f2bf(v);
                }
            }
        }
        asm volatile("s_barrier" ::: "memory");
        #pragma unroll
        for (int rr = 0; rr < 32; ++rr) {
            const int rl = wave * 32 + rr;
            const int swz = (rl & 7) << 2;
            shortx4 pk = *(shortx4*)&usc[rl * 256 + ((lane * 4) ^ swz)];
            *(shortx4*)&C[(size_t)(bm * 256 + rl) * N + bn * 256 + lane * 4] = pk;
        }
    }
}

// ---------------------------------------------------------------------------
// 128x256 tile, BK=64, 8-phase counted-vmcnt. FFN2 (512 blocks = 2 rounds).
// Coalesced f32 hf/hb epilogue (r15-verified: WRITE 153->98MB, 114.7->101us).
// ---------------------------------------------------------------------------
template<int EPI>
__global__ __launch_bounds__(512) void gemm128x256_bt(
    const unsigned short* __restrict__ A,
    const unsigned short* __restrict__ Bmat,
    unsigned short* __restrict__ C,
    const unsigned short* __restrict__ bias,
    float* __restrict__ hf,
    unsigned short* __restrict__ hb,
    int N, int K)
{
    __shared__ __align__(16) unsigned char smem[98304];
    unsigned short* AsB = (unsigned short*)smem;            // [2][8192]  (32 KB)
    unsigned short* BsB = (unsigned short*)(smem + 32768);  // [2][16384] (64 KB)

    const int t = threadIdx.x;           // 0..511
    const int lane = t & 63;
    const int wave = t >> 6;             // 0..7
    const int bm = blockIdx.x;
    const int bn = blockIdx.y;

    const int wm = (wave >> 2) * 64;
    const int wn = (wave & 3) * 64;

    const int srow = t >> 3;                               // 0..63
    const int scol = ((t & 7) ^ (srow & 7)) * 8;
    const unsigned short* Ag = A + (size_t)(bm * 128 + srow) * K + scol;
    const unsigned short* Bg = Bmat + (size_t)(bn * 256 + srow) * K + scol;
    const size_t rows64 = (size_t)64 * K;

    const int fl = lane & 15;
    const int g = lane >> 4;
    const int s7 = fl & 7;
    const int c0 = (g ^ s7) * 8;
    const int c1 = ((4 + g) ^ s7) * 8;
    const int abase = (wm + fl) * 64;
    const int bbase = (wn + fl) * 64;

    floatx4 acc[4][4];
    #pragma unroll
    for (int i = 0; i < 4; ++i)
        #pragma unroll
        for (int j = 0; j < 4; ++j) {
            acc[i][j][0] = 0.f; acc[i][j][1] = 0.f;
            acc[i][j][2] = 0.f; acc[i][j][3] = 0.f;
        }

    auto stgA = [&](int buf, size_t koff) {
        const unsigned short* s = Ag + koff;
        unsigned short* d = &AsB[buf * 8192 + t * 8];
        async_cp16(s, d);
        async_cp16(s + rows64, d + 4096);
    };
    auto stgB = [&](int buf, int h, size_t koff) {
        const unsigned short* s = Bg + (size_t)(h * 128) * K + koff;
        unsigned short* d = &BsB[buf * 16384 + h * 8192 + t * 8];
        async_cp16(s, d);
        async_cp16(s + rows64, d + 4096);
    };

    const int NT = K >> 6;

    stgA(0, 0); stgB(0, 0, 0); stgB(0, 1, 0);
    if (NT > 1) {
        stgA(1, 64);
        asm volatile("s_waitcnt vmcnt(2)" ::: "memory");
    } else {
        asm volatile("s_waitcnt vmcnt(0)" ::: "memory");
    }
    asm volatile("s_barrier" ::: "memory");

    for (int tt = 0; tt < NT; ++tt) {
        const int R = tt & 1;
        const int S = R ^ 1;
        const size_t k1 = (size_t)(tt + 1) << 6;
        const size_t k2 = (size_t)(tt + 2) << 6;
        const bool p1 = (tt + 1 < NT);
        const bool p2 = (tt + 2 < NT);

        short8 a0[4], a1[4], b0[4], b1[4];

        // ---- phase 1 ----
        #pragma unroll
        for (int i = 0; i < 4; ++i) a0[i] = *(const short8*)&AsB[R * 8192 + abase + i * 1024 + c0];
        #pragma unroll
        for (int j = 0; j < 4; ++j) b0[j] = *(const short8*)&BsB[R * 16384 + bbase + j * 1024 + c0];
        if (p1) stgB(S, 0, k1);
        asm volatile("s_barrier" ::: "memory");
        asm volatile("s_waitcnt lgkmcnt(0)" ::: "memory");
        __builtin_amdgcn_s_setprio(1);
        #pragma unroll
        for (int i = 0; i < 4; ++i) {
            acc[i][0] = mfma16(a0[i], b0[0], acc[i][0]);
            acc[i][1] = mfma16(a0[i], b0[1], acc[i][1]);
        }
        __builtin_amdgcn_s_setprio(0);
        asm volatile("s_barrier" ::: "memory");

        // ---- phase 2 ----
        #pragma unroll
        for (int i = 0; i < 4; ++i) a1[i] = *(const short8*)&AsB[R * 8192 + abase + i * 1024 + c1];
        #pragma unroll
        for (int j = 0; j < 4; ++j) b1[j] = *(const short8*)&BsB[R * 16384 + bbase + j * 1024 + c1];
        if (p1) stgB(S, 1, k1);
        asm volatile("s_barrier" ::: "memory");
        asm volatile("s_waitcnt lgkmcnt(0)" ::: "memory");   // all buf-R reads retired
        __builtin_amdgcn_s_setprio(1);
        #pragma unroll
        for (int i = 0; i < 4; ++i) {
            acc[i][2] = mfma16(a0[i], b0[2], acc[i][2]);
            acc[i][3] = mfma16(a0[i], b0[3], acc[i][3]);
        }
        __builtin_amdgcn_s_setprio(0);
        asm volatile("s_barrier" ::: "memory");

        // ---- phase 3 ----
        if (p2) stgA(R, k2);
        asm volatile("s_barrier" ::: "memory");
        __builtin_amdgcn_s_setprio(1);
        #pragma unroll
        for (int i = 0; i < 4; ++i) {
            acc[i][0] = mfma16(a1[i], b1[0], acc[i][0]);
            acc[i][1] = mfma16(a1[i], b1[1], acc[i][1]);
        }
        __builtin_amdgcn_s_setprio(0);
        asm volatile("s_barrier" ::: "memory");

        // ---- phase 4 ----
        __builtin_amdgcn_s_setprio(1);
        #pragma unroll
        for (int i = 0; i < 4; ++i) {
            acc[i][2] = mfma16(a1[i], b1[2], acc[i][2]);
            acc[i][3] = mfma16(a1[i], b1[3], acc[i][3]);
        }
        __builtin_amdgcn_s_setprio(0);
        if (p2) asm volatile("s_waitcnt vmcnt(2)" ::: "memory");
        else    asm volatile("s_waitcnt vmcnt(0)" ::: "memory");
        asm volatile("s_barrier" ::: "memory");
    }

    // coalesced epilogue: two 64-row halves via f32 LDS scratch [64][260]
    float* fsc = (float*)smem;
    for (int h = 0; h < 2; ++h) {
        asm volatile("s_barrier" ::: "memory");
        if ((wave >> 2) == h) {
            #pragma unroll
            for (int i = 0; i < 4; ++i)
                #pragma unroll
                for (int j = 0; j < 4; ++j)
                    #pragma unroll
                    for (int r = 0; r < 4; ++r)
                        fsc[(i * 16 + g * 4 + r) * 260 + wn + j * 16 + fl] = acc[i][j][r];
        }
        asm volatile("s_barrier" ::: "memory");
        #pragma unroll
        for (int rr = 0; rr < 8; ++rr) {
            const int rl = wave * 8 + rr;
            const int grow = bm * 128 + h * 64 + rl;
            const int gcol = bn * 256 + lane * 4;
            const size_t idx = (size_t)grow * N + gcol;
            floatx4 v = *(floatx4*)&fsc[rl * 260 + lane * 4];
            float b0v = 0.f, b1v = 0.f, b2v = 0.f, b3v = 0.f;
            if (EPI != EPI_NONE) {
                b0v = bf2f(bias[gcol]);     b1v = bf2f(bias[gcol + 1]);
                b2v = bf2f(bias[gcol + 2]); b3v = bf2f(bias[gcol + 3]);
            }
            if (EPI == EPI_BIAS_RES) {
                floatx4 hv = *(const floatx4*)&hf[idx];
                floatx4 nh;
                nh[0] = hv[0] + v[0] + b0v; nh[1] = hv[1] + v[1] + b1v;
                nh[2] = hv[2] + v[2] + b2v; nh[3] = hv[3] + v[3] + b3v;
                *(floatx4*)&hf[idx] = nh;
                shortx4 pk;
                pk[0] = (short)f2bf(nh[0]); pk[1] = (short)f2bf(nh[1]);
                pk[2] = (short)f2bf(nh[2]); pk[3] = (short)f2bf(nh[3]);
                *(shortx4*)&hb[idx] = pk;
            } else {
                float v0 = v[0], v1 = v[1], v2 = v[2], v3 = v[3];
                if (EPI == EPI_BIAS_RELU) {
                    v0 += b0v; v1 += b1v; v2 += b2v; v3 += b3v;
                    v0 = v0 > 0.f ? v0 : 0.f; v1 = v1 > 0.f ? v1 : 0.f;
                    v2 = v2 > 0.f ? v2 : 0.f; v3 = v3 > 0.f ? v3 : 0.f;
                }
                shortx4 pk;
                pk[0] = (short)f2bf(v0); pk[1] = (short)f2bf(v1);
                pk[2] = (short)f2bf(v2); pk[3] = (short)f2bf(v3);
                *(shortx4*)&C[idx] = pk;
            }
        }
    }
}

// MFMA flash attention (validated round 4). blockIdx = pair*4 + qquarter.
__global__ __launch_bounds__(128) void attn_mfma(
    const unsigned short* __restrict__ Q,
    const unsigned short* __restrict__ Kx,
    const unsigned short* __restrict__ Vx,
    const float* __restrict__ maskf,
    unsigned short* __restrict__ Out)
{
    __shared__ __align__(16) unsigned short Vt[16 * 520];
    __shared__ __align__(16) unsigned short Pb[2][64 * 40];
    __shared__ float Ms[512];
    __shared__ float cnt_s;

    const int t = threadIdx.x;
    const int lane = t & 63;
    const int wave = t >> 6;
    const int p = blockIdx.x >> 2;
    const int qq = blockIdx.x & 3;
    const int b2 = p & 31;
    const int h2 = p >> 5;
    const int fm = lane & 15;
    const int g = lane >> 4;

    const unsigned short* Qg = Q + (size_t)p * 8192;
    const unsigned short* Kg = Kx + (size_t)p * 8192;
    const unsigned short* Vg = Vx + (size_t)p * 8192;

    #pragma unroll
    for (int rr = 0; rr < 4; ++rr) {
        const int row = t * 4 + rr;
        short8 v0 = *(const short8*)&Vg[row * 16];
        short8 v1 = *(const short8*)&Vg[row * 16 + 8];
        #pragma unroll
        for (int d = 0; d < 8; ++d) Vt[d * 520 + row] = (unsigned short)v0[d];
        #pragma unroll
        for (int d = 0; d < 8; ++d) Vt[(d + 8) * 520 + row] = (unsigned short)v1[d];
    }
    if (t == 0) cnt_s = 0.f;
    __syncthreads();
    float pc = 0.f;
    #pragma unroll
    for (int it = 0; it < 4; ++it) {
        int i = it * 128 + t;
        float mv = maskf[b2 * 512 + i];
        Ms[i] = mv; pc += mv;
    }
    atomicAdd(&cnt_s, pc);
    __syncthreads();
    const float cnt = cnt_s;

    const int qbase = qq * 128 + wave * 64;
    short8 qf[4];
    #pragma unroll
    for (int i = 0; i < 4; ++i) {
        short8 z = {0,0,0,0,0,0,0,0};
        if (g < 2) z = *(const short8*)&Qg[(qbase + i * 16 + fm) * 16 + g * 8];
        qf[i] = z;
    }

    float m_[4][4], l_[4][4];
    floatx4 O[4];
    #pragma unroll
    for (int i = 0; i < 4; ++i) {
        #pragma unroll
        for (int r = 0; r < 4; ++r) { m_[i][r] = -1e30f; l_[i][r] = 0.f; }
        O[i][0] = 0.f; O[i][1] = 0.f; O[i][2] = 0.f; O[i][3] = 0.f;
    }

    unsigned short* Pw = &Pb[wave][0];

    for (int kb = 0; kb < 512; kb += 32) {
        short8 kf0 = {0,0,0,0,0,0,0,0}, kf1 = {0,0,0,0,0,0,0,0};
        if (g < 2) {
            kf0 = *(const short8*)&Kg[(kb + fm) * 16 + g * 8];
            kf1 = *(const short8*)&Kg[(kb + 16 + fm) * 16 + g * 8];
        }
        const float msk0 = Ms[kb + fm];
        const float msk1 = Ms[kb + 16 + fm];

        floatx4 zero4 = {0.f, 0.f, 0.f, 0.f};
        floatx4 s0[4], s1[4];
        #pragma unroll
        for (int i = 0; i < 4; ++i) {
            s0[i] = __builtin_amdgcn_mfma_f32_16x16x32_bf16(qf[i], kf0, zero4, 0, 0, 0);
            s1[i] = __builtin_amdgcn_mfma_f32_16x16x32_bf16(qf[i], kf1, zero4, 0, 0, 0);
        }

        #pragma unroll
        for (int i = 0; i < 4; ++i) {
            #pragma unroll
            for (int r = 0; r < 4; ++r) {
                float a0 = (msk0 != 0.f) ? -1e30f : s0[i][r] * NORM_;
                float a1 = (msk1 != 0.f) ? -1e30f : s1[i][r] * NORM_;
                float mx = fmaxf(a0, a1);
                mx = fmaxf(mx, __shfl_xor(mx, 1));
                mx = fmaxf(mx, __shfl_xor(mx, 2));
                mx = fmaxf(mx, __shfl_xor(mx, 4));
                mx = fmaxf(mx, __shfl_xor(mx, 8));
                const float mo = m_[i][r];
                const float mn = fmaxf(mo, mx);
                const float alpha = __expf(mo - mn);
                float w0 = (msk0 != 0.f) ? 0.f : __expf(a0 - mn);
                float w1 = (msk1 != 0.f) ? 0.f : __expf(a1 - mn);
                float rs = w0 + w1;
                rs += __shfl_xor(rs, 1);
                rs += __shfl_xor(rs, 2);
                rs += __shfl_xor(rs, 4);
                rs += __shfl_xor(rs, 8);
                l_[i][r] = l_[i][r] * alpha + rs;
                m_[i][r] = mn;
                O[i][r] *= alpha;
                const int qloc = i * 16 + g * 4 + r;
                Pw[qloc * 40 + fm] = f2bf(w0);
                Pw[qloc * 40 + 16 + fm] = f2bf(w1);
            }
        }
        asm volatile("s_waitcnt lgkmcnt(0)" ::: "memory");

        short8 vtf = *(const short8*)&Vt[fm * 520 + kb + g * 8];
        #pragma unroll
        for (int i = 0; i < 4; ++i) {
            short8 pf = *(const short8*)&Pw[(i * 16 + fm) * 40 + g * 8];
            O[i] = __builtin_amdgcn_mfma_f32_16x16x32_bf16(pf, vtf, O[i], 0, 0, 0);
        }
    }

    #pragma unroll
    for (int i = 0; i < 4; ++i) {
        #pragma unroll
        for (int r = 0; r < 4; ++r) {
            const float M = fmaxf(m_[i][r], -30.f);
            const float adj = __expf(m_[i][r] - M);
            const float lf = l_[i][r] * adj + cnt * __expf(-30.f - M);
            const float oval = O[i][r] * adj / lf;
            const int n = qbase + i * 16 + g * 4 + r;
            Out[((size_t)(b2 * 512 + n)) * 128 + h2 * 16 + fm] = f2bf(oval);
        }
    }
}

__global__ __launch_bounds__(256) void write_h(const float* __restrict__ hf,
                                               void* __restrict__ out,
                                               const int* __restrict__ flag)
{
    const size_t i = ((size_t)blockIdx.x * 256 + threadIdx.x) * 4;
    floatx4 v = *(const floatx4*)&hf[i];
    if (*flag) {
        *(floatx4*)((float*)out + i) = v;
    } else {
        unsigned int p0 = (unsigned int)f2bf(v[0]) | ((unsigned int)f2bf(v[1]) << 16);
        unsigned int p1 = (unsigned int)f2bf(v[2]) | ((unsigned int)f2bf(v[3]) << 16);
        unsigned int* o = (unsigned int*)((unsigned short*)out + i);
        o[0] = p0; o[1] = p1;
    }
}

__global__ __launch_bounds__(256) void mean_kernel(const float* __restrict__ hf,
                                                   void* __restrict__ out,
                                                   const int* __restrict__ flag)
{
    const int b = blockIdx.x >> 2;
    const int e = ((blockIdx.x & 3) * 256) + threadIdx.x;
    float s = 0.f;
    for (int n = 0; n < 512; ++n) s += hf[((size_t)(b * 512 + n)) * 1024 + e];
    s *= (1.0f / 512.0f);
    const size_t off = (size_t)16384 * 1024 + b * 1024 + e;
    if (*flag) ((float*)out)[off] = s;
    else       ((unsigned short*)out)[off] = f2bf(s);
}

extern "C" void kernel_launch(void* const* d_in, const int* in_sizes, int n_in,
                              void* d_out, int out_size, void* d_ws, size_t ws_size,
                              hipStream_t stream)
{
    const void* x  = d_in[0];
    const unsigned int* mask = (const unsigned int*)d_in[1];

    char* ws = (char*)d_ws;
    float* hf = (float*)ws;                     ws += (size_t)16384 * 1024 * 4;   // 64 MB
    unsigned short* hb = (unsigned short*)ws;   ws += (size_t)16384 * 1024 * 2;   // 32 MB
    char* shared_rg = ws;                       ws += (size_t)16384 * 2048 * 2;   // 64 MB
    unsigned short* act = (unsigned short*)shared_rg;
    unsigned short* q  = (unsigned short*)shared_rg;
    unsigned short* k  = q + (size_t)16384 * 128;
    unsigned short* v  = k + (size_t)16384 * 128;
    unsigned short* ao = v + (size_t)16384 * 128;
    unsigned short* cWq = (unsigned short*)ws;  ws += (size_t)393216 * 2;
    unsigned short* cWk = (unsigned short*)ws;  ws += (size_t)393216 * 2;
    unsigned short* cWv = (unsigned short*)ws;  ws += (size_t)393216 * 2;
    unsigned short* cWo = (unsigned short*)ws;  ws += (size_t)393216 * 2;
    unsigned short* cbo = (unsigned short*)ws;  ws += (size_t)3072 * 2;
    unsigned short* cW1 = (unsigned short*)ws;  ws += (size_t)6291456 * 2;
    unsigned short* cb1 = (unsigned short*)ws;  ws += (size_t)6144 * 2;
    unsigned short* cW2 = (unsigned short*)ws;  ws += (size_t)6291456 * 2;
    unsigned short* cb2 = (unsigned short*)ws;  ws += (size_t)3072 * 2;
    float* maskf = (float*)ws;                  ws += (size_t)16384 * 4;
    int* flag = (int*)ws;                       ws += 256;

    detect_dtype<<<1, 256, 0, stream>>>((const unsigned int*)x, flag);

    auto conv = [&](const void* s, unsigned short* d, int n) {
        conv_to_bf16<<<(n / 8 + 255) / 256, 256, 0, stream>>>(s, d, n, flag);
    };
    conv(d_in[2], cWq, 393216);
    conv(d_in[3], cWk, 393216);
    conv(d_in[4], cWv, 393216);
    conv(d_in[5], cWo, 393216);
    conv(d_in[6], cbo, 3072);
    conv(d_in[7], cW1, 6291456);
    conv(d_in[8], cb1, 6144);
    conv(d_in[9], cW2, 6291456);
    conv(d_in[10], cb2, 3072);

    mask_expand<<<64, 256, 0, stream>>>(mask, maskf);
    init_h<<<8192, 256, 0, stream>>>(x, hf, hb, flag);

    for (int l = 0; l < 3; ++l) {
        const unsigned short* wq  = cWq + (size_t)l * 131072;
        const unsigned short* wk  = cWk + (size_t)l * 131072;
        const unsigned short* wv  = cWv + (size_t)l * 131072;
        const unsigned short* wo  = cWo + (size_t)l * 131072;
        const unsigned short* bol = cbo + (size_t)l * 1024;
        const unsigned short* w1  = cW1 + (size_t)l * 2097152;
        const unsigned short* b1l = cb1 + (size_t)l * 2048;
        const unsigned short* w2  = cW2 + (size_t)l * 2097152;
        const unsigned short* b2l = cb2 + (size_t)l * 1024;

        gemm_bt<EPI_NONE><<<dim3(128, 1, 3), 256, 0, stream>>>(
            hb, wq, wk, wv, q, k, v, nullptr, nullptr, nullptr, 128, 1024);
        attn_mfma<<<1024, 128, 0, stream>>>(q, k, v, maskf, ao);
        // Wo: now with coalesced residual epilogue
        gemm_bt<EPI_BIAS_RES><<<dim3(128, 8, 1), 256, 0, stream>>>(
            ao, wo, wo, wo, nullptr, nullptr, nullptr, bol, hf, hb, 1024, 128);
        // FFN1: 256^2 8-phase + coalesced C epilogue
        gemm256_bt<EPI_BIAS_RELU><<<dim3(64, 8, 1), 512, 0, stream>>>(
            hb, w1, act, b1l, nullptr, nullptr, 2048, 1024);
        // FFN2: 128x256 8-phase + coalesced hf/hb epilogue
        gemm128x256_bt<EPI_BIAS_RES><<<dim3(128, 4, 1), 512, 0, stream>>>(
            act, w2, nullptr, b2l, hf, hb, 1024, 2048);
    }

    write_h<<<16384, 256, 0, stream>>>(hf, d_out, flag);
    mean_kernel<<<128, 256, 0, stream>>>(hf, d_out, flag);
}